// Round 17
// baseline (549.286 us; speedup 1.0000x reference)
//
#include <hip/hip_runtime.h>
#include <hip/hip_bf16.h>
#include <cstdint>
#include <math.h>

#define DEV static __device__ __forceinline__

typedef __attribute__((ext_vector_type(8))) __bf16 bf16x8v;
typedef __attribute__((ext_vector_type(4))) float f32x4;

constexpr int B = 4, T = 512, BT = B * T;
constexpr int D_MODEL = 769, D_INNER = 1538, D2 = 3076;
constexpr int DT_RANK = 49, D_STATE = 64;
constexpr int NCH = 8, CHT = 64;           // fused scan: 8 chunks x 64 t
constexpr int SDG = 12;                    // scan d-group size
constexpr int DG12 = (D_INNER + SDG - 1) / SDG;  // 129 -> grid 516 = 2.02 blocks/CU
constexpr int THALO = 539;                 // 13 + 512 + 14 halo rows per b
// padded GEMM dims (K multiple of 64, N multiple of 128)
constexpr int KP_MODEL = 832;   // 769
constexpr int KP_INNER = 1600;  // 1538
constexpr int KP_DT    = 64;    // 49
constexpr int NP_IN  = 3200;    // 3076
constexpr int NP_X   = 256;     // 177
constexpr int NP_DT  = 1664;    // 1538
constexpr int NP_OUT = 896;     // 769
constexpr int KCONV  = 3456;    // 27*128 unified front-conv reduction
constexpr int NCONV  = 768;

DEV float fexp2(float x) { return __builtin_amdgcn_exp2f(x); }   // raw v_exp_f32
DEV float flog2(float x) { return __builtin_amdgcn_logf(x); }    // raw v_log_f32
DEV float frcp(float x) { return __builtin_amdgcn_rcpf(x); }     // raw v_rcp_f32
DEV float siluf(float v) { return v * frcp(1.f + fexp2(-1.44269504f * v)); }
DEV float softplusf(float v) {
  return fmaxf(v, 0.f) + 0.69314718f * flog2(1.f + fexp2(-1.44269504f * fabsf(v)));
}

DEV float wredx(float v) {
#pragma unroll
  for (int o = 1; o < 64; o <<= 1) v += __shfl_xor(v, o);
  return v;
}

// DPP / swizzle cross-lane helpers (VALU-pipe DPP where possible)
#define DPPF(v, ctrl) __uint_as_float((uint)__builtin_amdgcn_mov_dpp((int)__float_as_uint(v), (ctrl), 0xf, 0xf, true))
#define SWZF(v, pat) __uint_as_float((uint)__builtin_amdgcn_ds_swizzle((int)__float_as_uint(v), (pat)))

DEV void gload_lds16(const void* g, void* l) {
  __builtin_amdgcn_global_load_lds(
      (const __attribute__((address_space(1))) uint32_t*)(uintptr_t)g,
      (__attribute__((address_space(3))) uint32_t*)(uint32_t)(uintptr_t)l,
      16, 0, 0);
}

// ---------------- front end ----------------

// x (B,T,65) -> hpbfH (B,539,128) halo'd, rows 13..524 = silu(pointconv)
__global__ void front_pointconv(const float* __restrict__ x, const float* __restrict__ pw,
                                const float* __restrict__ pb, __hip_bfloat16* __restrict__ hpbfH) {
  int t = blockIdx.x, b = blockIdx.y, c = threadIdx.x;  // 128 threads
  __shared__ float xs[64];
  if (c < 64) xs[c] = x[((size_t)b * T + t) * 65 + c];
  __syncthreads();
  float acc = pb[c];
  const float4* pwr = (const float4*)(pw + c * 64);
#pragma unroll
  for (int i = 0; i < 16; ++i) {
    float4 w4 = pwr[i];
    acc = fmaf(w4.x, xs[4 * i + 0], acc);
    acc = fmaf(w4.y, xs[4 * i + 1], acc);
    acc = fmaf(w4.z, xs[4 * i + 2], acc);
    acc = fmaf(w4.w, xs[4 * i + 3], acc);
  }
  hpbfH[((size_t)b * THALO + 13 + t) * 128 + c] = __float2bfloat16(siluf(acc));
}

// zero halo rows 0..12 and 525..538 of each b
__global__ void zero_halo(__hip_bfloat16* __restrict__ h) {
  int i = blockIdx.x * 256 + threadIdx.x;
  if (i >= B * 27 * 128) return;
  int b = i / (27 * 128), r = i - b * 27 * 128;
  int row = r >> 7, c = r & 127;
  int rr = (row < 13) ? row : row + 512;
  h[((size_t)b * THALO + rr) * 128 + c] = __float2bfloat16(0.f);
}

// c1w/c2w/c3w -> Wfr(768, 3456) bf16; tail range fills bias vector
__global__ void build_conv_wb(const float* __restrict__ c1w, const float* __restrict__ c2w,
                              const float* __restrict__ c3w, const float* __restrict__ b1,
                              const float* __restrict__ b2, const float* __restrict__ b3,
                              __hip_bfloat16* __restrict__ Wfr, float* __restrict__ cb) {
  int total = NCONV * KCONV;
  for (int idx = blockIdx.x * 256 + threadIdx.x; idx < total + NCONV; idx += gridDim.x * 256) {
    if (idx < total) {
      int co = idx / KCONV, r = idx - co * KCONV;
      int j = r >> 7, ci = r & 127;
      float v = 0.f;
      if (co < 256) {
        int k = j - 12;
        if (k >= 0 && k < 3) v = c1w[((size_t)co * 128 + ci) * 3 + k];
      } else if (co < 512) {
        int k = j - 9;
        if (k >= 0 && k < 9) v = c2w[((size_t)(co - 256) * 128 + ci) * 9 + k];
      } else {
        v = c3w[((size_t)(co - 512) * 128 + ci) * 27 + j];
      }
      Wfr[idx] = __float2bfloat16(v);
    } else {
      int i = idx - total;
      cb[i] = (i < 256) ? b1[i] : (i < 512) ? b2[i - 256] : b3[i - 512];
    }
  }
}

// ---------------- weight conversion, all tensors both layers, 1 launch ----------------
__global__ void cvt_all(const float* __restrict__ Wi, const float* __restrict__ Wx,
                        const float* __restrict__ Wdt, const float* __restrict__ Wo,
                        __hip_bfloat16* __restrict__ Wibf, __hip_bfloat16* __restrict__ Wxbf,
                        __hip_bfloat16* __restrict__ Wdtbf, __hip_bfloat16* __restrict__ Wobf) {
  int l = blockIdx.y >> 2, t = blockIdx.y & 3;
  const float* src;
  __hip_bfloat16* dst;
  int N, K, Npad, Kpad;
  if (t == 0) { src = Wi + (size_t)l * D2 * D_MODEL; dst = Wibf + (size_t)l * NP_IN * KP_MODEL;
                N = D2; K = D_MODEL; Npad = NP_IN; Kpad = KP_MODEL; }
  else if (t == 1) { src = Wx + (size_t)l * (DT_RANK + 2 * D_STATE) * D_INNER;
                dst = Wxbf + (size_t)l * NP_X * KP_INNER;
                N = DT_RANK + 2 * D_STATE; K = D_INNER; Npad = NP_X; Kpad = KP_INNER; }
  else if (t == 2) { src = Wdt + (size_t)l * D_INNER * DT_RANK; dst = Wdtbf + (size_t)l * NP_DT * KP_DT;
                N = D_INNER; K = DT_RANK; Npad = NP_DT; Kpad = KP_DT; }
  else { src = Wo + (size_t)l * D_MODEL * D_INNER; dst = Wobf + (size_t)l * NP_OUT * KP_INNER;
                N = D_MODEL; K = D_INNER; Npad = NP_OUT; Kpad = KP_INNER; }
  int total = Npad * Kpad;
  for (int idx = blockIdx.x * 256 + threadIdx.x; idx < total; idx += gridDim.x * 256) {
    int n = idx / Kpad, k = idx - n * Kpad;
    float v = (n < N && k < K) ? src[(size_t)n * K + k] : 0.f;
    dst[idx] = __float2bfloat16(v);
  }
}

__global__ void zero_pad_cols(__hip_bfloat16* __restrict__ buf, int rows, int ld, int c0) {
  int w = ld - c0;
  int total = rows * w;
  int idx = blockIdx.x * 256 + threadIdx.x;
  if (idx < total) buf[(size_t)(idx / w) * ld + c0 + (idx % w)] = __float2bfloat16(0.f);
}

// ---------------- bf16 MFMA GEMM:  C[m][n] = sum_k A[m][k] * W[n][k] (+ epilogue) ----------------
// EPI 1: softplus(acc+bias[n]) -> dtdu float2 {dt, dt*du} in (b,t,d);
// 6: split-K raw partial store; 7: bf16 store to auxb[m*ldc+n]
// CONV=1: A is halo'd hpbfH with row stride 256B (im2col-free front conv).
// XCD-aware swizzle: weight-panel-major chunking so each XCD touches few N-panels.
template <int EPI, int CONV = 0>
__global__ __launch_bounds__(256) void gemm_bf16(const __hip_bfloat16* __restrict__ A,
                                                 const __hip_bfloat16* __restrict__ W,
                                                 float* __restrict__ C, int M, int Nreal, int Kp,
                                                 const float* extra, int ldadd, int ldc,
                                                 float2* auxv, __hip_bfloat16* auxb,
                                                 const __hip_bfloat16* auxr) {
  __shared__ __align__(16) __hip_bfloat16 As[128 * 64];
  __shared__ __align__(16) __hip_bfloat16 Bs[128 * 64];
  const int tid = threadIdx.x;
  const int wid = tid >> 6, lane = tid & 63;
  const int wr = wid >> 1, wc = wid & 1;
  int bx = blockIdx.x, by = blockIdx.y;
  {
    int gx = gridDim.x, gy = gridDim.y;
    int nwg = gx * gy;
    if ((nwg & 7) == 0) {
      int hid = by * gx + bx;                 // hw dispatch linear id (x fastest)
      int wkl = (hid & 7) * (nwg >> 3) + (hid >> 3);  // XCD k owns contiguous chunk
      bx = wkl / gy;                          // column-major: chunk = few bx (weight panels)
      by = wkl - bx * gy;
    }
  }
  const int m0 = by * 128, n0 = bx * 128;
  f32x4 acc[4][4] = {};
  const int lrow = lane >> 3;                                 // row within 8-row segment
  const int cbyte = ((lane & 7) << 4) ^ (lrow << 4);          // inverse-swizzled source col byte
  const char* Wb = (const char*)W;
  const size_t strideB = (size_t)Kp * 2;
  const char* ArowBase;
  size_t sA;
  if constexpr (CONV) {
    int brow = m0 >> 9;
    ArowBase = (const char*)A + (size_t)(brow * THALO + (m0 & 511)) * 256;
    sA = 256;
  } else {
    ArowBase = (const char*)A + (size_t)m0 * strideB;
    sA = strideB;
  }
  const int swz = (lane & 7) << 4;

  int kbeg = 0, kend = Kp;
  if constexpr (EPI == 6) {
    int khalf = (((Kp >> 1) + 63) >> 6) << 6;
    if (blockIdx.z == 0) kend = khalf; else kbeg = khalf;
  }

  for (int k0 = kbeg; k0 < kend; k0 += 64) {
#pragma unroll
    for (int i = 0; i < 4; ++i) {
      int seg = i * 4 + wid;                                  // wave-uniform
      int row = seg * 8 + lrow;
      gload_lds16(ArowBase + (size_t)row * sA + k0 * 2 + cbyte, (char*)As + seg * 1024);
      gload_lds16(Wb + (size_t)(n0 + row) * strideB + k0 * 2 + cbyte, (char*)Bs + seg * 1024);
    }
    __syncthreads();
#pragma unroll
    for (int kk = 0; kk < 2; ++kk) {
      int kb = kk * 64 + ((lane >> 4) << 4);                  // byte offset of this lane's 8 bf16
      bf16x8v af[4], bfr[4];
#pragma unroll
      for (int mi = 0; mi < 4; ++mi) {
        int row = wr * 64 + mi * 16 + (lane & 15);
        af[mi] = *(const bf16x8v*)((const char*)As + row * 128 + (kb ^ swz));
      }
#pragma unroll
      for (int ni = 0; ni < 4; ++ni) {
        int row = wc * 64 + ni * 16 + (lane & 15);
        bfr[ni] = *(const bf16x8v*)((const char*)Bs + row * 128 + (kb ^ swz));
      }
#pragma unroll
      for (int mi = 0; mi < 4; ++mi)
#pragma unroll
        for (int ni = 0; ni < 4; ++ni)
          acc[mi][ni] = __builtin_amdgcn_mfma_f32_16x16x32_bf16(af[mi], bfr[ni], acc[mi][ni], 0, 0, 0);
    }
    __syncthreads();
  }

#pragma unroll
  for (int mi = 0; mi < 4; ++mi) {
#pragma unroll
    for (int ni = 0; ni < 4; ++ni) {
      int n = n0 + wc * 64 + ni * 16 + (lane & 15);
      if (n < Nreal) {
        int mb = m0 + wr * 64 + mi * 16 + ((lane >> 4) << 2);
#pragma unroll
        for (int v = 0; v < 4; ++v) {
          float val = acc[mi][ni][v];
          int m = mb + v;
          if constexpr (EPI == 1) {
            val = softplusf(val + extra[n]);
            float du = __bfloat162float(auxr[(size_t)m * KP_INNER + n]);
            auxv[(size_t)m * D_INNER + n] = make_float2(val, val * du);   // (b,t,d) coalesced
          } else if constexpr (EPI == 6) {
            C[((size_t)blockIdx.z * M + m) * ldc + n] = val;
          } else if constexpr (EPI == 7) {
            auxb[(size_t)m * ldc + n] = __float2bfloat16(val);
          } else {
            C[(size_t)m * ldc + n] = val;
          }
        }
      }
    }
  }
}

// ---------------- fused combine kernels (block per row) ----------------
// front conv combine + silu + pe + rmsnorm -> hbuf, ubf
__global__ __launch_bounds__(256) void combine_conv_rms(const float* __restrict__ p,
                                                        const float* __restrict__ cb,
                                                        const float* __restrict__ x,
                                                        const float* __restrict__ rmsw,
                                                        float* __restrict__ h,
                                                        __hip_bfloat16* __restrict__ ubf) {
  int m = blockIdx.x;
  __shared__ float sh[D_MODEL];
  __shared__ float red[4];
  int wid = threadIdx.x >> 6, lane = threadIdx.x & 63;
  float ss = 0.f;
  for (int n = threadIdx.x; n < D_MODEL; n += 256) {
    float v;
    if (n < NCONV)
      v = siluf(p[(size_t)m * NCONV + n] + p[(size_t)BT * NCONV + (size_t)m * NCONV + n] + cb[n]);
    else
      v = x[(size_t)m * 65 + 64];
    sh[n] = v;
    h[(size_t)m * D_MODEL + n] = v;
    ss = fmaf(v, v, ss);
  }
  ss = wredx(ss);
  if (lane == 0) red[wid] = ss;
  __syncthreads();
  float sc = rsqrtf((red[0] + red[1] + red[2] + red[3]) * (1.f / D_MODEL) + 1e-6f);
  for (int i = threadIdx.x; i < KP_MODEL; i += 256) {
    float v = (i < D_MODEL) ? sh[i] * sc * rmsw[i] : 0.f;
    ubf[(size_t)m * KP_MODEL + i] = __float2bfloat16(v);
  }
}

// out_proj combine + residual + rmsnorm(next layer) -> hbuf, ubf
__global__ __launch_bounds__(256) void combine_out_rms(const float* __restrict__ p,
                                                       const float* __restrict__ rmsw,
                                                       float* __restrict__ h,
                                                       __hip_bfloat16* __restrict__ ubf) {
  int m = blockIdx.x;
  __shared__ float sh[D_MODEL];
  __shared__ float red[4];
  int wid = threadIdx.x >> 6, lane = threadIdx.x & 63;
  float ss = 0.f;
  for (int n = threadIdx.x; n < D_MODEL; n += 256) {
    size_t i = (size_t)m * D_MODEL + n;
    float v = h[i] + p[i] + p[(size_t)BT * D_MODEL + i];
    sh[n] = v;
    h[i] = v;
    ss = fmaf(v, v, ss);
  }
  ss = wredx(ss);
  if (lane == 0) red[wid] = ss;
  __syncthreads();
  float sc = rsqrtf((red[0] + red[1] + red[2] + red[3]) * (1.f / D_MODEL) + 1e-6f);
  for (int i = threadIdx.x; i < KP_MODEL; i += 256) {
    float v = (i < D_MODEL) ? sh[i] * sc * rmsw[i] : 0.f;
    ubf[(size_t)m * KP_MODEL + i] = __float2bfloat16(v);
  }
}

// last layer: out_proj combine + residual + layernorm + classifier head -> out
__global__ __launch_bounds__(256) void combine_ln(const float* __restrict__ p,
                                                  const float* __restrict__ h,
                                                  const float* __restrict__ lnw,
                                                  const float* __restrict__ lnb,
                                                  const float* __restrict__ ow,
                                                  const float* __restrict__ ob,
                                                  float* __restrict__ out) {
  int row = blockIdx.x;
  __shared__ float sh[D_MODEL];
  __shared__ float red[4];
  int wid = threadIdx.x >> 6, lane = threadIdx.x & 63;
  float s = 0.f;
  for (int i = threadIdx.x; i < D_MODEL; i += 256) {
    size_t ix = (size_t)row * D_MODEL + i;
    float v = h[ix] + p[ix] + p[(size_t)BT * D_MODEL + ix];
    sh[i] = v;
    s += v;
  }
  s = wredx(s);
  if (lane == 0) red[wid] = s;
  __syncthreads();
  float mean = (red[0] + red[1] + red[2] + red[3]) * (1.f / D_MODEL);
  __syncthreads();
  float vs = 0.f;
  for (int i = threadIdx.x; i < D_MODEL; i += 256) { float dd = sh[i] - mean; vs = fmaf(dd, dd, vs); }
  vs = wredx(vs);
  if (lane == 0) red[wid] = vs;
  __syncthreads();
  float var = (red[0] + red[1] + red[2] + red[3]) * (1.f / D_MODEL);
  float inv = rsqrtf(var + 1e-5f);
  for (int i = threadIdx.x; i < D_MODEL; i += 256)
    sh[i] = (sh[i] - mean) * inv * lnw[i] + lnb[i];
  __syncthreads();
  for (int c = wid; c < 10; c += 4) {
    float acc = 0.f;
    for (int i = lane; i < D_MODEL; i += 64) acc = fmaf(sh[i], ow[(size_t)c * D_MODEL + i], acc);
    acc = wredx(acc);
    if (lane == 0) out[(size_t)row * 10 + c] = acc + ob[c];
  }
}

// x_proj combine: parts (2, BT, 256) -> dtbf (BT,64) bf16 + bcbf (BT,64) packed {B,C} bf16x2
__global__ void combine_xproj(const float* __restrict__ p, __hip_bfloat16* __restrict__ dtbf,
                              __hip_bfloat16* __restrict__ bcb) {
  int i = blockIdx.x * 256 + threadIdx.x;
  if (i >= BT * 192) return;
  int m = i / 192, n = i - m * 192;
  if (n >= DT_RANK + 2 * D_STATE) return;
  float v = p[(size_t)m * 256 + n] + p[(size_t)(BT + m) * 256 + n];
  if (n < 64) dtbf[(size_t)m * 64 + n] = __float2bfloat16(n < DT_RANK ? v : 0.f);
  if (n >= DT_RANK && n < DT_RANK + D_STATE)
    bcb[((size_t)m * 64 + (n - DT_RANK)) * 2] = __float2bfloat16(v);          // B -> lo
  else if (n >= DT_RANK + D_STATE)
    bcb[((size_t)m * 64 + (n - DT_RANK - D_STATE)) * 2 + 1] = __float2bfloat16(v);  // C -> hi
}

// ---------------- depthwise causal conv (k=4) + silu, 2 d per thread (packed) ----------------
__global__ void dwconv_silu(const __hip_bfloat16* __restrict__ xz, const float* __restrict__ cw,
                            const float* __restrict__ cb, __hip_bfloat16* __restrict__ xinbf) {
  int idx = blockIdx.x * 256 + threadIdx.x;
  if (idx >= BT * 769) return;                 // D_INNER/2 pairs
  int bt = idx / 769;
  int dd = idx - bt * 769;                     // pair index; d = 2*dd, d+1
  int d = dd * 2;
  int t = bt & (T - 1);
  float4 w0 = *(const float4*)(cw + (size_t)d * 4);
  float4 w1 = *(const float4*)(cw + (size_t)(d + 1) * 4);
  float acc0 = cb[d], acc1 = cb[d + 1];
  const uint* col = (const uint*)(xz + (size_t)bt * D2) + dd;
  float wk0[4] = {w0.x, w0.y, w0.z, w0.w};
  float wk1[4] = {w1.x, w1.y, w1.z, w1.w};
#pragma unroll
  for (int k = 0; k < 4; ++k) {
    int tt = t + k - 3;
    uint v = (tt >= 0) ? col[(ptrdiff_t)(k - 3) * (D2 / 2)] : 0u;
    float lo = __uint_as_float(v << 16);
    float hi = __uint_as_float(v & 0xffff0000u);
    acc0 = fmaf(wk0[k], lo, acc0);
    acc1 = fmaf(wk1[k], hi, acc1);
  }
  acc0 = siluf(acc0);
  acc1 = siluf(acc1);
  uint lo16 = (__float_as_uint(acc0) + 0x8000u) >> 16;   // RTN-ish bf16 pack
  uint hi16 = (__float_as_uint(acc1) + 0x8000u) & 0xffff0000u;
  ((uint*)xinbf)[(size_t)bt * (KP_INNER / 2) + dd] = lo16 | hi16;
}

// ---------------- fused single-pass scan: 384 threads, 6 waves x 2 d/wave, 12 d/block ----------------
// grid = B*129 = 516 blocks = 2.02 blocks/CU -> even packing (r16 ran 1.51/CU, 24% occ).
// Each wave carries TWO independent h chains; LDS staging double-buffered per 64-t chunk;
// bc via register ping-pong with pointer-bump literal offsets. Reduce: DPP + 3 DS ops.

#define XSTR 13

#define FCOMP2(REG, T0L, T0G)                                                \
  {                                                                          \
    float4 qa0 = *(const float4*)&dtsA[(T0L)];                               \
    float4 qa1 = *(const float4*)&dtsA[(T0L) + 4];                           \
    float4 ua0 = *(const float4*)&dtusA[(T0L)];                              \
    float4 ua1 = *(const float4*)&dtusA[(T0L) + 4];                          \
    float4 qb0 = *(const float4*)&dtsB[(T0L)];                               \
    float4 qb1 = *(const float4*)&dtsB[(T0L) + 4];                           \
    float4 ub0 = *(const float4*)&dtusB[(T0L)];                              \
    float4 ub1 = *(const float4*)&dtusB[(T0L) + 4];                          \
    float dtvA[8] = {qa0.x, qa0.y, qa0.z, qa0.w, qa1.x, qa1.y, qa1.z, qa1.w};\
    float duvA[8] = {ua0.x, ua0.y, ua0.z, ua0.w, ua1.x, ua1.y, ua1.z, ua1.w};\
    float dtvB[8] = {qb0.x, qb0.y, qb0.z, qb0.w, qb1.x, qb1.y, qb1.z, qb1.w};\
    float duvB[8] = {ub0.x, ub0.y, ub0.z, ub0.w, ub1.x, ub1.y, ub1.z, ub1.w};\
    float vvA[8], vvB[8];                                                    \
    _Pragma("unroll") for (int k = 0; k < 8; ++k) {                          \
      float Bv = __uint_as_float(REG[k] << 16);                              \
      float Cv = __uint_as_float(REG[k] & 0xffff0000u);                      \
      hA = fmaf(fexp2(dtvA[k] * a2A), hA, duvA[k] * Bv);                     \
      hB = fmaf(fexp2(dtvB[k] * a2B), hB, duvB[k] * Bv);                     \
      vvA[k] = hA * Cv;                                                      \
      vvB[k] = hB * Cv;                                                      \
    }                                                                        \
    _Pragma("unroll") for (int k = 0; k < 4; ++k) {                          \
      float sA = bb0 ? vvA[k] : vvA[k + 4];                                  \
      float kA = bb0 ? vvA[k + 4] : vvA[k];                                  \
      vvA[k] = kA + DPPF(sA, 0xB1);                                          \
      float sB = bb0 ? vvB[k] : vvB[k + 4];                                  \
      float kB = bb0 ? vvB[k + 4] : vvB[k];                                  \
      vvB[k] = kB + DPPF(sB, 0xB1);                                          \
    }                                                                        \
    _Pragma("unroll") for (int k = 0; k < 2; ++k) {                          \
      float sA = bb1 ? vvA[k] : vvA[k + 2];                                  \
      float kA = bb1 ? vvA[k + 2] : vvA[k];                                  \
      vvA[k] = kA + DPPF(sA, 0x4E);                                          \
      float sB = bb1 ? vvB[k] : vvB[k + 2];                                  \
      float kB = bb1 ? vvB[k + 2] : vvB[k];                                  \
      vvB[k] = kB + DPPF(sB, 0x4E);                                          \
    }                                                                        \
    {                                                                        \
      float sA = bb2 ? vvA[0] : vvA[1];                                      \
      float kA = bb2 ? vvA[1] : vvA[0];                                      \
      vvA[0] = kA + SWZF(sA, 0x101F);                                        \
      float sB = bb2 ? vvB[0] : vvB[1];                                      \
      float kB = bb2 ? vvB[1] : vvB[0];                                      \
      vvB[0] = kB + SWZF(sB, 0x101F);                                        \
    }                                                                        \
    float yA = vvA[0], yB = vvB[0];                                          \
    yA += DPPF(yA, 0x128);  yB += DPPF(yB, 0x128);                           \
    yA += SWZF(yA, 0x401F); yB += SWZF(yB, 0x401F);                          \
    yA += __shfl_xor(yA, 32); yB += __shfl_xor(yB, 32);                      \
    if (lane < 8) {                                                          \
      int trow = ((T0L) + brl) * XSTR;                                       \
      if (vA) {                                                              \
        float yo = (yA + xinS[trow + 2 * wid] * dskA) * siluf(xzS[trow + 2 * wid]); \
        ybf[(rb + (T0G) + brl) * KP_INNER + dA] = __float2bfloat16(yo);      \
      }                                                                      \
      if (vB) {                                                              \
        float yo = (yB + xinS[trow + 2 * wid + 1] * dskB) * siluf(xzS[trow + 2 * wid + 1]); \
        ybf[(rb + (T0G) + brl) * KP_INNER + dB] = __float2bfloat16(yo);      \
      }                                                                      \
    }                                                                        \
  }

__global__ __launch_bounds__(384) void scan_fused(const uint* __restrict__ bcp16,
                                                  const float2* __restrict__ dtdu,
                                                  const __hip_bfloat16* __restrict__ xinbf,
                                                  const __hip_bfloat16* __restrict__ xzbf,
                                                  const float* __restrict__ A_log,
                                                  const float* __restrict__ Dskip,
                                                  __hip_bfloat16* __restrict__ ybf) {
  __shared__ __align__(16) float dts[2][SDG * 68];
  __shared__ __align__(16) float dtus[2][SDG * 68];
  __shared__ float xins[2][CHT * XSTR];
  __shared__ float xzs[2][CHT * XSTR];
  int tid = threadIdx.x, wid = tid >> 6, lane = tid & 63;
  int dg = blockIdx.x % DG12, b = blockIdx.x / DG12;
  int d0 = dg * SDG;
  int dA = d0 + wid * 2, dB = dA + 1;
  bool vA = (dA < D_INNER), vB = (dB < D_INNER);
  int dcA = vA ? dA : (D_INNER - 1);
  int dcB = vB ? dB : (D_INNER - 1);
  const size_t rb = (size_t)b * T;

  auto stage = [&](int c, int s) {
#pragma unroll
    for (int j = 0; j < 2; ++j) {
      int t2 = tid + j * 384;                       // CHT*SDG = 768 = 2*384
      int stt = t2 / SDG, sdd = t2 - stt * SDG;
      int dcl = d0 + sdd;  if (dcl >= D_INNER) dcl = D_INNER - 1;
      float2 dq = dtdu[(rb + c * CHT + stt) * D_INNER + dcl];
      dts[s][sdd * 68 + stt] = dq.x;
      dtus[s][sdd * 68 + stt] = dq.y;
      xins[s][stt * XSTR + sdd] = __bfloat162float(xinbf[(rb + c * CHT + stt) * KP_INNER + d0 + sdd]);
      xzs[s][stt * XSTR + sdd] = __bfloat162float(xzbf[(rb + c * CHT + stt) * D2 + D_INNER + d0 + sdd]);
    }
  };

  stage(0, 0);

  const bool bb2 = lane & 4, bb1 = lane & 2, bb0 = lane & 1;
  const int brl = ((lane & 1) << 2) | (lane & 2) | ((lane & 4) >> 2);
  float a2A = -__expf(A_log[(size_t)dcA * D_STATE + lane]) * 1.44269504f;
  float a2B = -__expf(A_log[(size_t)dcB * D_STATE + lane]) * 1.44269504f;
  float dskA = Dskip[dcA], dskB = Dskip[dcB];
  float hA = 0.f, hB = 0.f;
  const uint* bgp = bcp16 + rb * 64 + lane;

  __syncthreads();

  uint bA[8], bB[8];
#pragma unroll
  for (int k = 0; k < 8; ++k) bA[k] = bgp[k * 64];
  const uint* bq = bgp;  // pointer-bump: advances 1024 elems (16 t) per group

  for (int ch = 0; ch < NCH; ++ch) {
    int s = ch & 1;
    const float* dtsA = &dts[s][(2 * wid) * 68];
    const float* dtusA = &dtus[s][(2 * wid) * 68];
    const float* dtsB = &dts[s][(2 * wid + 1) * 68];
    const float* dtusB = &dtus[s][(2 * wid + 1) * 68];
    const float* xinS = &xins[s][0];
    const float* xzS = &xzs[s][0];
    if (ch + 1 < NCH) stage(ch + 1, s ^ 1);
#pragma unroll
    for (int gi = 0; gi < 4; ++gi) {
      int t0l = gi * 16;
      int t0g = ch * CHT + t0l;
#pragma unroll
      for (int k = 0; k < 8; ++k) bB[k] = bq[512 + k * 64];   // literal offsets 2048..3840B
      FCOMP2(bA, t0l, t0g);
      bq += 1024;
      if (!(ch == NCH - 1 && gi == 3)) {
#pragma unroll
        for (int k = 0; k < 8; ++k) bA[k] = bq[k * 64];       // literal offsets 0..1792B
      }
      FCOMP2(bB, t0l + 8, t0g + 8);
    }
    __syncthreads();
  }
}

// ---------------- launcher ----------------
extern "C" void kernel_launch(void* const* d_in, const int* in_sizes, int n_in,
                              void* d_out, int out_size, void* d_ws, size_t ws_size,
                              hipStream_t stream) {
  const float* x    = (const float*)d_in[0];
  const float* pcw  = (const float*)d_in[1];
  const float* pcb  = (const float*)d_in[2];
  const float* c1w  = (const float*)d_in[3];
  const float* c1b  = (const float*)d_in[4];
  const float* c2w  = (const float*)d_in[5];
  const float* c2b  = (const float*)d_in[6];
  const float* c3w  = (const float*)d_in[7];
  const float* c3b  = (const float*)d_in[8];
  const float* lnw  = (const float*)d_in[9];
  const float* lnb  = (const float*)d_in[10];
  const float* ow   = (const float*)d_in[11];
  const float* ob   = (const float*)d_in[12];
  const float* rmsw = (const float*)d_in[13];
  const float* Wi   = (const float*)d_in[14];
  const float* dww  = (const float*)d_in[15];
  const float* dwb  = (const float*)d_in[16];
  const float* Wx   = (const float*)d_in[17];
  const float* Wdt  = (const float*)d_in[18];
  const float* dtbv = (const float*)d_in[19];
  const float* Alog = (const float*)d_in[20];
  const float* Dsk  = (const float*)d_in[21];
  const float* Wo   = (const float*)d_in[22];
  float* out = (float*)d_out;

  char* w = (char*)d_ws;
  auto alloc = [&](size_t n) { char* p = w; w += (n + 255) & ~(size_t)255; return p; };
  // shared region: front-end buffers (dead after front GEMM) aliased with scan temps
  constexpr size_t REGION = 26400000;
  char* region = alloc(REGION);
  __hip_bfloat16* hpbfH = (__hip_bfloat16*)region;                   // 552,448 B (halo'd)
  __hip_bfloat16* Wfr  = (__hip_bfloat16*)(region + 14756096);       // 5,308,416 B
  float* cb768         = (float*)(region + 20065024);                // 3,072 B
  float2* dtduT        = (float2*)region;                            // 25,198,592 B (layer phase)
  __hip_bfloat16* bcbf = (__hip_bfloat16*)(region + 25198592);       // 524,288 B packed {B,C}

  float* hbuf          = (float*)alloc((size_t)BT * D_MODEL * 4);
  __hip_bfloat16* ubf  = (__hip_bfloat16*)alloc((size_t)BT * KP_MODEL * 2);
  __hip_bfloat16* xzbf = (__hip_bfloat16*)alloc((size_t)BT * D2 * 2);
  __hip_bfloat16* xinbf= (__hip_bfloat16*)alloc((size_t)BT * KP_INNER * 2);
  __hip_bfloat16* dtbf = (__hip_bfloat16*)alloc((size_t)BT * KP_DT * 2);
  __hip_bfloat16* ybf  = (__hip_bfloat16*)alloc((size_t)BT * KP_INNER * 2);
  __hip_bfloat16* Wibf = (__hip_bfloat16*)alloc((size_t)2 * NP_IN * KP_MODEL * 2);
  __hip_bfloat16* Wxbf = (__hip_bfloat16*)alloc((size_t)2 * NP_X * KP_INNER * 2);
  __hip_bfloat16* Wdtbf= (__hip_bfloat16*)alloc((size_t)2 * NP_DT * KP_DT * 2);
  __hip_bfloat16* Wobf = (__hip_bfloat16*)alloc((size_t)2 * NP_OUT * KP_INNER * 2);
  float* parts         = (float*)alloc((size_t)2 * BT * D_MODEL * 4);          // 12.6 MB split-K partials

  zero_halo<<<(B * 27 * 128 + 255) / 256, 256, 0, stream>>>(hpbfH);
  front_pointconv<<<dim3(T, B), 128, 0, stream>>>(x, pcw, pcb, hpbfH);
  build_conv_wb<<<2048, 256, 0, stream>>>(c1w, c2w, c3w, c1b, c2b, c3b, Wfr, cb768);
  cvt_all<<<dim3(1024, 8), 256, 0, stream>>>(Wi, Wx, Wdt, Wo, Wibf, Wxbf, Wdtbf, Wobf);
  gemm_bf16<6, 1><<<dim3(NCONV / 128, BT / 128, 2), 256, 0, stream>>>(
      hpbfH, Wfr, parts, BT, NCONV, KCONV, nullptr, 0, NCONV, nullptr, nullptr, nullptr);
  combine_conv_rms<<<BT, 256, 0, stream>>>(parts, cb768, x, rmsw, hbuf, ubf);
  // pad columns written once (scan/dwconv never touch cols >= D_INNER)
  zero_pad_cols<<<(BT * (KP_INNER - D_INNER) + 255) / 256, 256, 0, stream>>>(xinbf, BT, KP_INNER, D_INNER);
  zero_pad_cols<<<(BT * (KP_INNER - D_INNER) + 255) / 256, 256, 0, stream>>>(ybf, BT, KP_INNER, D_INNER);

  for (int l = 0; l < 2; ++l) {
    const float* Al = Alog + (size_t)l * D_INNER * D_STATE;
    gemm_bf16<7><<<dim3(NP_IN / 128, BT / 128), 256, 0, stream>>>(
        ubf, Wibf + (size_t)l * NP_IN * KP_MODEL, nullptr, BT, D2, KP_MODEL,
        nullptr, 0, D2, nullptr, xzbf, nullptr);
    dwconv_silu<<<(BT * 769 + 255) / 256, 256, 0, stream>>>(xzbf, dww + (size_t)l * D_INNER * 4,
                                                            dwb + (size_t)l * D_INNER, xinbf);
    gemm_bf16<6><<<dim3(NP_X / 128, BT / 128, 2), 256, 0, stream>>>(
        xinbf, Wxbf + (size_t)l * NP_X * KP_INNER, parts, BT,
        DT_RANK + 2 * D_STATE, KP_INNER, nullptr, 0, 256, nullptr, nullptr, nullptr);
    combine_xproj<<<(BT * 192 + 255) / 256, 256, 0, stream>>>(parts, dtbf, bcbf);
    gemm_bf16<1><<<dim3(NP_DT / 128, BT / 128), 256, 0, stream>>>(
        dtbf, Wdtbf + (size_t)l * NP_DT * KP_DT, nullptr, BT, D_INNER, KP_DT,
        dtbv + (size_t)l * D_INNER, 0, 0, dtduT, nullptr, xinbf);
    scan_fused<<<dim3(B * DG12), 384, 0, stream>>>((const uint*)bcbf, dtduT, xinbf, xzbf, Al,
                                                   Dsk + (size_t)l * D_INNER, ybf);
    gemm_bf16<6><<<dim3(NP_OUT / 128, BT / 128, 2), 256, 0, stream>>>(
        ybf, Wobf + (size_t)l * NP_OUT * KP_INNER, parts, BT, D_MODEL, KP_INNER,
        nullptr, 0, D_MODEL, nullptr, nullptr, nullptr);
    if (l == 0) {
      combine_out_rms<<<BT, 256, 0, stream>>>(parts, rmsw + D_MODEL, hbuf, ubf);
    } else {
      combine_ln<<<BT, 256, 0, stream>>>(parts, hbuf, lnw, lnb, ow, ob, out);
    }
  }
}

// Round 18
// 474.325 us; speedup vs baseline: 1.1580x; 1.1580x over previous
//
#include <hip/hip_runtime.h>
#include <hip/hip_bf16.h>
#include <cstdint>
#include <math.h>

#define DEV static __device__ __forceinline__

typedef __attribute__((ext_vector_type(8))) __bf16 bf16x8v;
typedef __attribute__((ext_vector_type(4))) float f32x4;

constexpr int B = 4, T = 512, BT = B * T;
constexpr int D_MODEL = 769, D_INNER = 1538, D2 = 3076;
constexpr int DT_RANK = 49, D_STATE = 64;
constexpr int NCH = 8, CHT = 64;           // fused scan: 8 chunks x 64 t
constexpr int DGRP = (D_INNER + 15) / 16;  // 97 d-groups of 16
constexpr int THALO = 539;                 // 13 + 512 + 14 halo rows per b
// padded GEMM dims (K multiple of 64, N multiple of 128)
constexpr int KP_MODEL = 832;   // 769
constexpr int KP_INNER = 1600;  // 1538
constexpr int KP_DT    = 64;    // 49
constexpr int NP_IN  = 3200;    // 3076
constexpr int NP_X   = 256;     // 177
constexpr int NP_DT  = 1664;    // 1538
constexpr int NP_OUT = 896;     // 769
constexpr int KCONV  = 3456;    // 27*128 unified front-conv reduction
constexpr int NCONV  = 768;

DEV float fexp2(float x) { return __builtin_amdgcn_exp2f(x); }   // raw v_exp_f32
DEV float flog2(float x) { return __builtin_amdgcn_logf(x); }    // raw v_log_f32
DEV float frcp(float x) { return __builtin_amdgcn_rcpf(x); }     // raw v_rcp_f32
DEV float siluf(float v) { return v * frcp(1.f + fexp2(-1.44269504f * v)); }
DEV float softplusf(float v) {
  return fmaxf(v, 0.f) + 0.69314718f * flog2(1.f + fexp2(-1.44269504f * fabsf(v)));
}

DEV float wredx(float v) {
#pragma unroll
  for (int o = 1; o < 64; o <<= 1) v += __shfl_xor(v, o);
  return v;
}

// DPP / swizzle cross-lane helpers (VALU-pipe DPP where possible)
#define DPPF(v, ctrl) __uint_as_float((uint)__builtin_amdgcn_mov_dpp((int)__float_as_uint(v), (ctrl), 0xf, 0xf, true))
#define SWZF(v, pat) __uint_as_float((uint)__builtin_amdgcn_ds_swizzle((int)__float_as_uint(v), (pat)))

DEV void gload_lds16(const void* g, void* l) {
  __builtin_amdgcn_global_load_lds(
      (const __attribute__((address_space(1))) uint32_t*)(uintptr_t)g,
      (__attribute__((address_space(3))) uint32_t*)(uint32_t)(uintptr_t)l,
      16, 0, 0);
}

// ---------------- front end ----------------

// x (B,T,65) -> hpbfH (B,539,128) halo'd, rows 13..524 = silu(pointconv)
__global__ void front_pointconv(const float* __restrict__ x, const float* __restrict__ pw,
                                const float* __restrict__ pb, __hip_bfloat16* __restrict__ hpbfH) {
  int t = blockIdx.x, b = blockIdx.y, c = threadIdx.x;  // 128 threads
  __shared__ float xs[64];
  if (c < 64) xs[c] = x[((size_t)b * T + t) * 65 + c];
  __syncthreads();
  float acc = pb[c];
  const float4* pwr = (const float4*)(pw + c * 64);
#pragma unroll
  for (int i = 0; i < 16; ++i) {
    float4 w4 = pwr[i];
    acc = fmaf(w4.x, xs[4 * i + 0], acc);
    acc = fmaf(w4.y, xs[4 * i + 1], acc);
    acc = fmaf(w4.z, xs[4 * i + 2], acc);
    acc = fmaf(w4.w, xs[4 * i + 3], acc);
  }
  hpbfH[((size_t)b * THALO + 13 + t) * 128 + c] = __float2bfloat16(siluf(acc));
}

// zero halo rows 0..12 and 525..538 of each b
__global__ void zero_halo(__hip_bfloat16* __restrict__ h) {
  int i = blockIdx.x * 256 + threadIdx.x;
  if (i >= B * 27 * 128) return;
  int b = i / (27 * 128), r = i - b * 27 * 128;
  int row = r >> 7, c = r & 127;
  int rr = (row < 13) ? row : row + 512;
  h[((size_t)b * THALO + rr) * 128 + c] = __float2bfloat16(0.f);
}

// c1w/c2w/c3w -> Wfr(768, 3456) bf16; tail range fills bias vector
__global__ void build_conv_wb(const float* __restrict__ c1w, const float* __restrict__ c2w,
                              const float* __restrict__ c3w, const float* __restrict__ b1,
                              const float* __restrict__ b2, const float* __restrict__ b3,
                              __hip_bfloat16* __restrict__ Wfr, float* __restrict__ cb) {
  int total = NCONV * KCONV;
  for (int idx = blockIdx.x * 256 + threadIdx.x; idx < total + NCONV; idx += gridDim.x * 256) {
    if (idx < total) {
      int co = idx / KCONV, r = idx - co * KCONV;
      int j = r >> 7, ci = r & 127;
      float v = 0.f;
      if (co < 256) {
        int k = j - 12;
        if (k >= 0 && k < 3) v = c1w[((size_t)co * 128 + ci) * 3 + k];
      } else if (co < 512) {
        int k = j - 9;
        if (k >= 0 && k < 9) v = c2w[((size_t)(co - 256) * 128 + ci) * 9 + k];
      } else {
        v = c3w[((size_t)(co - 512) * 128 + ci) * 27 + j];
      }
      Wfr[idx] = __float2bfloat16(v);
    } else {
      int i = idx - total;
      cb[i] = (i < 256) ? b1[i] : (i < 512) ? b2[i - 256] : b3[i - 512];
    }
  }
}

// ---------------- weight conversion, all tensors both layers, 1 launch ----------------
__global__ void cvt_all(const float* __restrict__ Wi, const float* __restrict__ Wx,
                        const float* __restrict__ Wdt, const float* __restrict__ Wo,
                        __hip_bfloat16* __restrict__ Wibf, __hip_bfloat16* __restrict__ Wxbf,
                        __hip_bfloat16* __restrict__ Wdtbf, __hip_bfloat16* __restrict__ Wobf) {
  int l = blockIdx.y >> 2, t = blockIdx.y & 3;
  const float* src;
  __hip_bfloat16* dst;
  int N, K, Npad, Kpad;
  if (t == 0) { src = Wi + (size_t)l * D2 * D_MODEL; dst = Wibf + (size_t)l * NP_IN * KP_MODEL;
                N = D2; K = D_MODEL; Npad = NP_IN; Kpad = KP_MODEL; }
  else if (t == 1) { src = Wx + (size_t)l * (DT_RANK + 2 * D_STATE) * D_INNER;
                dst = Wxbf + (size_t)l * NP_X * KP_INNER;
                N = DT_RANK + 2 * D_STATE; K = D_INNER; Npad = NP_X; Kpad = KP_INNER; }
  else if (t == 2) { src = Wdt + (size_t)l * D_INNER * DT_RANK; dst = Wdtbf + (size_t)l * NP_DT * KP_DT;
                N = D_INNER; K = DT_RANK; Npad = NP_DT; Kpad = KP_DT; }
  else { src = Wo + (size_t)l * D_MODEL * D_INNER; dst = Wobf + (size_t)l * NP_OUT * KP_INNER;
                N = D_MODEL; K = D_INNER; Npad = NP_OUT; Kpad = KP_INNER; }
  int total = Npad * Kpad;
  for (int idx = blockIdx.x * 256 + threadIdx.x; idx < total; idx += gridDim.x * 256) {
    int n = idx / Kpad, k = idx - n * Kpad;
    float v = (n < N && k < K) ? src[(size_t)n * K + k] : 0.f;
    dst[idx] = __float2bfloat16(v);
  }
}

__global__ void zero_pad_cols(__hip_bfloat16* __restrict__ buf, int rows, int ld, int c0) {
  int w = ld - c0;
  int total = rows * w;
  int idx = blockIdx.x * 256 + threadIdx.x;
  if (idx < total) buf[(size_t)(idx / w) * ld + c0 + (idx % w)] = __float2bfloat16(0.f);
}

// ---------------- bf16 MFMA GEMM:  C[m][n] = sum_k A[m][k] * W[n][k] (+ epilogue) ----------------
// EPI 1: softplus(acc+bias[n]) -> dtdu float2 {dt, dt*du} in (b,t,d);
// 6: split-K raw partial store; 7: bf16 store to auxb[m*ldc+n]
// CONV=1: A is halo'd hpbfH with row stride 256B (im2col-free front conv).
// XCD-aware swizzle: weight-panel-major chunking so each XCD touches few N-panels.
template <int EPI, int CONV = 0>
__global__ __launch_bounds__(256) void gemm_bf16(const __hip_bfloat16* __restrict__ A,
                                                 const __hip_bfloat16* __restrict__ W,
                                                 float* __restrict__ C, int M, int Nreal, int Kp,
                                                 const float* extra, int ldadd, int ldc,
                                                 float2* auxv, __hip_bfloat16* auxb,
                                                 const __hip_bfloat16* auxr) {
  __shared__ __align__(16) __hip_bfloat16 As[128 * 64];
  __shared__ __align__(16) __hip_bfloat16 Bs[128 * 64];
  const int tid = threadIdx.x;
  const int wid = tid >> 6, lane = tid & 63;
  const int wr = wid >> 1, wc = wid & 1;
  int bx = blockIdx.x, by = blockIdx.y;
  {
    int gx = gridDim.x, gy = gridDim.y;
    int nwg = gx * gy;
    if ((nwg & 7) == 0) {
      int hid = by * gx + bx;                 // hw dispatch linear id (x fastest)
      int wkl = (hid & 7) * (nwg >> 3) + (hid >> 3);  // XCD k owns contiguous chunk
      bx = wkl / gy;                          // column-major: chunk = few bx (weight panels)
      by = wkl - bx * gy;
    }
  }
  const int m0 = by * 128, n0 = bx * 128;
  f32x4 acc[4][4] = {};
  const int lrow = lane >> 3;                                 // row within 8-row segment
  const int cbyte = ((lane & 7) << 4) ^ (lrow << 4);          // inverse-swizzled source col byte
  const char* Wb = (const char*)W;
  const size_t strideB = (size_t)Kp * 2;
  const char* ArowBase;
  size_t sA;
  if constexpr (CONV) {
    int brow = m0 >> 9;
    ArowBase = (const char*)A + (size_t)(brow * THALO + (m0 & 511)) * 256;
    sA = 256;
  } else {
    ArowBase = (const char*)A + (size_t)m0 * strideB;
    sA = strideB;
  }
  const int swz = (lane & 7) << 4;

  int kbeg = 0, kend = Kp;
  if constexpr (EPI == 6) {
    int khalf = (((Kp >> 1) + 63) >> 6) << 6;
    if (blockIdx.z == 0) kend = khalf; else kbeg = khalf;
  }

  for (int k0 = kbeg; k0 < kend; k0 += 64) {
#pragma unroll
    for (int i = 0; i < 4; ++i) {
      int seg = i * 4 + wid;                                  // wave-uniform
      int row = seg * 8 + lrow;
      gload_lds16(ArowBase + (size_t)row * sA + k0 * 2 + cbyte, (char*)As + seg * 1024);
      gload_lds16(Wb + (size_t)(n0 + row) * strideB + k0 * 2 + cbyte, (char*)Bs + seg * 1024);
    }
    __syncthreads();
#pragma unroll
    for (int kk = 0; kk < 2; ++kk) {
      int kb = kk * 64 + ((lane >> 4) << 4);                  // byte offset of this lane's 8 bf16
      bf16x8v af[4], bfr[4];
#pragma unroll
      for (int mi = 0; mi < 4; ++mi) {
        int row = wr * 64 + mi * 16 + (lane & 15);
        af[mi] = *(const bf16x8v*)((const char*)As + row * 128 + (kb ^ swz));
      }
#pragma unroll
      for (int ni = 0; ni < 4; ++ni) {
        int row = wc * 64 + ni * 16 + (lane & 15);
        bfr[ni] = *(const bf16x8v*)((const char*)Bs + row * 128 + (kb ^ swz));
      }
#pragma unroll
      for (int mi = 0; mi < 4; ++mi)
#pragma unroll
        for (int ni = 0; ni < 4; ++ni)
          acc[mi][ni] = __builtin_amdgcn_mfma_f32_16x16x32_bf16(af[mi], bfr[ni], acc[mi][ni], 0, 0, 0);
    }
    __syncthreads();
  }

#pragma unroll
  for (int mi = 0; mi < 4; ++mi) {
#pragma unroll
    for (int ni = 0; ni < 4; ++ni) {
      int n = n0 + wc * 64 + ni * 16 + (lane & 15);
      if (n < Nreal) {
        int mb = m0 + wr * 64 + mi * 16 + ((lane >> 4) << 2);
#pragma unroll
        for (int v = 0; v < 4; ++v) {
          float val = acc[mi][ni][v];
          int m = mb + v;
          if constexpr (EPI == 1) {
            val = softplusf(val + extra[n]);
            float du = __bfloat162float(auxr[(size_t)m * KP_INNER + n]);
            auxv[(size_t)m * D_INNER + n] = make_float2(val, val * du);   // (b,t,d) coalesced
          } else if constexpr (EPI == 6) {
            C[((size_t)blockIdx.z * M + m) * ldc + n] = val;
          } else if constexpr (EPI == 7) {
            auxb[(size_t)m * ldc + n] = __float2bfloat16(val);
          } else {
            C[(size_t)m * ldc + n] = val;
          }
        }
      }
    }
  }
}

// ---------------- fused combine kernels (block per row) ----------------
// front conv combine + silu + pe + rmsnorm -> hbuf, ubf
__global__ __launch_bounds__(256) void combine_conv_rms(const float* __restrict__ p,
                                                        const float* __restrict__ cb,
                                                        const float* __restrict__ x,
                                                        const float* __restrict__ rmsw,
                                                        float* __restrict__ h,
                                                        __hip_bfloat16* __restrict__ ubf) {
  int m = blockIdx.x;
  __shared__ float sh[D_MODEL];
  __shared__ float red[4];
  int wid = threadIdx.x >> 6, lane = threadIdx.x & 63;
  float ss = 0.f;
  for (int n = threadIdx.x; n < D_MODEL; n += 256) {
    float v;
    if (n < NCONV)
      v = siluf(p[(size_t)m * NCONV + n] + p[(size_t)BT * NCONV + (size_t)m * NCONV + n] + cb[n]);
    else
      v = x[(size_t)m * 65 + 64];
    sh[n] = v;
    h[(size_t)m * D_MODEL + n] = v;
    ss = fmaf(v, v, ss);
  }
  ss = wredx(ss);
  if (lane == 0) red[wid] = ss;
  __syncthreads();
  float sc = rsqrtf((red[0] + red[1] + red[2] + red[3]) * (1.f / D_MODEL) + 1e-6f);
  for (int i = threadIdx.x; i < KP_MODEL; i += 256) {
    float v = (i < D_MODEL) ? sh[i] * sc * rmsw[i] : 0.f;
    ubf[(size_t)m * KP_MODEL + i] = __float2bfloat16(v);
  }
}

// out_proj combine + residual + rmsnorm(next layer) -> hbuf, ubf
__global__ __launch_bounds__(256) void combine_out_rms(const float* __restrict__ p,
                                                       const float* __restrict__ rmsw,
                                                       float* __restrict__ h,
                                                       __hip_bfloat16* __restrict__ ubf) {
  int m = blockIdx.x;
  __shared__ float sh[D_MODEL];
  __shared__ float red[4];
  int wid = threadIdx.x >> 6, lane = threadIdx.x & 63;
  float ss = 0.f;
  for (int n = threadIdx.x; n < D_MODEL; n += 256) {
    size_t i = (size_t)m * D_MODEL + n;
    float v = h[i] + p[i] + p[(size_t)BT * D_MODEL + i];
    sh[n] = v;
    h[i] = v;
    ss = fmaf(v, v, ss);
  }
  ss = wredx(ss);
  if (lane == 0) red[wid] = ss;
  __syncthreads();
  float sc = rsqrtf((red[0] + red[1] + red[2] + red[3]) * (1.f / D_MODEL) + 1e-6f);
  for (int i = threadIdx.x; i < KP_MODEL; i += 256) {
    float v = (i < D_MODEL) ? sh[i] * sc * rmsw[i] : 0.f;
    ubf[(size_t)m * KP_MODEL + i] = __float2bfloat16(v);
  }
}

// last layer: out_proj combine + residual + layernorm + classifier head -> out
__global__ __launch_bounds__(256) void combine_ln(const float* __restrict__ p,
                                                  const float* __restrict__ h,
                                                  const float* __restrict__ lnw,
                                                  const float* __restrict__ lnb,
                                                  const float* __restrict__ ow,
                                                  const float* __restrict__ ob,
                                                  float* __restrict__ out) {
  int row = blockIdx.x;
  __shared__ float sh[D_MODEL];
  __shared__ float red[4];
  int wid = threadIdx.x >> 6, lane = threadIdx.x & 63;
  float s = 0.f;
  for (int i = threadIdx.x; i < D_MODEL; i += 256) {
    size_t ix = (size_t)row * D_MODEL + i;
    float v = h[ix] + p[ix] + p[(size_t)BT * D_MODEL + ix];
    sh[i] = v;
    s += v;
  }
  s = wredx(s);
  if (lane == 0) red[wid] = s;
  __syncthreads();
  float mean = (red[0] + red[1] + red[2] + red[3]) * (1.f / D_MODEL);
  __syncthreads();
  float vs = 0.f;
  for (int i = threadIdx.x; i < D_MODEL; i += 256) { float dd = sh[i] - mean; vs = fmaf(dd, dd, vs); }
  vs = wredx(vs);
  if (lane == 0) red[wid] = vs;
  __syncthreads();
  float var = (red[0] + red[1] + red[2] + red[3]) * (1.f / D_MODEL);
  float inv = rsqrtf(var + 1e-5f);
  for (int i = threadIdx.x; i < D_MODEL; i += 256)
    sh[i] = (sh[i] - mean) * inv * lnw[i] + lnb[i];
  __syncthreads();
  for (int c = wid; c < 10; c += 4) {
    float acc = 0.f;
    for (int i = lane; i < D_MODEL; i += 64) acc = fmaf(sh[i], ow[(size_t)c * D_MODEL + i], acc);
    acc = wredx(acc);
    if (lane == 0) out[(size_t)row * 10 + c] = acc + ob[c];
  }
}

// x_proj combine: parts (2, BT, 256) -> dtbf (BT,64) bf16 + bcbf (BT,64) packed {B,C} bf16x2
__global__ void combine_xproj(const float* __restrict__ p, __hip_bfloat16* __restrict__ dtbf,
                              __hip_bfloat16* __restrict__ bcb) {
  int i = blockIdx.x * 256 + threadIdx.x;
  if (i >= BT * 192) return;
  int m = i / 192, n = i - m * 192;
  if (n >= DT_RANK + 2 * D_STATE) return;
  float v = p[(size_t)m * 256 + n] + p[(size_t)(BT + m) * 256 + n];
  if (n < 64) dtbf[(size_t)m * 64 + n] = __float2bfloat16(n < DT_RANK ? v : 0.f);
  if (n >= DT_RANK && n < DT_RANK + D_STATE)
    bcb[((size_t)m * 64 + (n - DT_RANK)) * 2] = __float2bfloat16(v);          // B -> lo
  else if (n >= DT_RANK + D_STATE)
    bcb[((size_t)m * 64 + (n - DT_RANK - D_STATE)) * 2 + 1] = __float2bfloat16(v);  // C -> hi
}

// ---------------- depthwise causal conv (k=4) + silu, 2 d per thread (packed) ----------------
__global__ void dwconv_silu(const __hip_bfloat16* __restrict__ xz, const float* __restrict__ cw,
                            const float* __restrict__ cb, __hip_bfloat16* __restrict__ xinbf) {
  int idx = blockIdx.x * 256 + threadIdx.x;
  if (idx >= BT * 769) return;                 // D_INNER/2 pairs
  int bt = idx / 769;
  int dd = idx - bt * 769;                     // pair index; d = 2*dd, d+1
  int d = dd * 2;
  int t = bt & (T - 1);
  float4 w0 = *(const float4*)(cw + (size_t)d * 4);
  float4 w1 = *(const float4*)(cw + (size_t)(d + 1) * 4);
  float acc0 = cb[d], acc1 = cb[d + 1];
  const uint* col = (const uint*)(xz + (size_t)bt * D2) + dd;
  float wk0[4] = {w0.x, w0.y, w0.z, w0.w};
  float wk1[4] = {w1.x, w1.y, w1.z, w1.w};
#pragma unroll
  for (int k = 0; k < 4; ++k) {
    int tt = t + k - 3;
    uint v = (tt >= 0) ? col[(ptrdiff_t)(k - 3) * (D2 / 2)] : 0u;
    float lo = __uint_as_float(v << 16);
    float hi = __uint_as_float(v & 0xffff0000u);
    acc0 = fmaf(wk0[k], lo, acc0);
    acc1 = fmaf(wk1[k], hi, acc1);
  }
  acc0 = siluf(acc0);
  acc1 = siluf(acc1);
  uint lo16 = (__float_as_uint(acc0) + 0x8000u) >> 16;   // RTN-ish bf16 pack
  uint hi16 = (__float_as_uint(acc1) + 0x8000u) & 0xffff0000u;
  ((uint*)xinbf)[(size_t)bt * (KP_INNER / 2) + dd] = lo16 | hi16;
}

// ---------------- fused single-pass scan: 512 threads, 8 waves x 2 d/wave, 16 d/block ----------------
// r16 config (measured optimum of 16d/512t=104, 8d/256t=108, 12d/384t=145 µs).
// Each wave carries TWO independent h chains; LDS staging double-buffered per 64-t chunk;
// bc via register ping-pong with pointer-bump literal offsets. Reduce: DPP + 3 DS ops.

#define FCOMP2(REG, T0L, T0G)                                                \
  {                                                                          \
    float4 qa0 = *(const float4*)&dtsA[(T0L)];                               \
    float4 qa1 = *(const float4*)&dtsA[(T0L) + 4];                           \
    float4 ua0 = *(const float4*)&dtusA[(T0L)];                              \
    float4 ua1 = *(const float4*)&dtusA[(T0L) + 4];                          \
    float4 qb0 = *(const float4*)&dtsB[(T0L)];                               \
    float4 qb1 = *(const float4*)&dtsB[(T0L) + 4];                           \
    float4 ub0 = *(const float4*)&dtusB[(T0L)];                              \
    float4 ub1 = *(const float4*)&dtusB[(T0L) + 4];                          \
    float dtvA[8] = {qa0.x, qa0.y, qa0.z, qa0.w, qa1.x, qa1.y, qa1.z, qa1.w};\
    float duvA[8] = {ua0.x, ua0.y, ua0.z, ua0.w, ua1.x, ua1.y, ua1.z, ua1.w};\
    float dtvB[8] = {qb0.x, qb0.y, qb0.z, qb0.w, qb1.x, qb1.y, qb1.z, qb1.w};\
    float duvB[8] = {ub0.x, ub0.y, ub0.z, ub0.w, ub1.x, ub1.y, ub1.z, ub1.w};\
    float vvA[8], vvB[8];                                                    \
    _Pragma("unroll") for (int k = 0; k < 8; ++k) {                          \
      float Bv = __uint_as_float(REG[k] << 16);                              \
      float Cv = __uint_as_float(REG[k] & 0xffff0000u);                      \
      hA = fmaf(fexp2(dtvA[k] * a2A), hA, duvA[k] * Bv);                     \
      hB = fmaf(fexp2(dtvB[k] * a2B), hB, duvB[k] * Bv);                     \
      vvA[k] = hA * Cv;                                                      \
      vvB[k] = hB * Cv;                                                      \
    }                                                                        \
    _Pragma("unroll") for (int k = 0; k < 4; ++k) {                          \
      float sA = bb0 ? vvA[k] : vvA[k + 4];                                  \
      float kA = bb0 ? vvA[k + 4] : vvA[k];                                  \
      vvA[k] = kA + DPPF(sA, 0xB1);                                          \
      float sB = bb0 ? vvB[k] : vvB[k + 4];                                  \
      float kB = bb0 ? vvB[k + 4] : vvB[k];                                  \
      vvB[k] = kB + DPPF(sB, 0xB1);                                          \
    }                                                                        \
    _Pragma("unroll") for (int k = 0; k < 2; ++k) {                          \
      float sA = bb1 ? vvA[k] : vvA[k + 2];                                  \
      float kA = bb1 ? vvA[k + 2] : vvA[k];                                  \
      vvA[k] = kA + DPPF(sA, 0x4E);                                          \
      float sB = bb1 ? vvB[k] : vvB[k + 2];                                  \
      float kB = bb1 ? vvB[k + 2] : vvB[k];                                  \
      vvB[k] = kB + DPPF(sB, 0x4E);                                          \
    }                                                                        \
    {                                                                        \
      float sA = bb2 ? vvA[0] : vvA[1];                                      \
      float kA = bb2 ? vvA[1] : vvA[0];                                      \
      vvA[0] = kA + SWZF(sA, 0x101F);                                        \
      float sB = bb2 ? vvB[0] : vvB[1];                                      \
      float kB = bb2 ? vvB[1] : vvB[0];                                      \
      vvB[0] = kB + SWZF(sB, 0x101F);                                        \
    }                                                                        \
    float yA = vvA[0], yB = vvB[0];                                          \
    yA += DPPF(yA, 0x128);  yB += DPPF(yB, 0x128);                           \
    yA += SWZF(yA, 0x401F); yB += SWZF(yB, 0x401F);                          \
    yA += __shfl_xor(yA, 32); yB += __shfl_xor(yB, 32);                      \
    if (lane < 8) {                                                          \
      int trow = ((T0L) + brl) * 17;                                         \
      if (vA) {                                                              \
        float yo = (yA + xinS[trow + 2 * wid] * dskA) * siluf(xzS[trow + 2 * wid]); \
        ybf[(rb + (T0G) + brl) * KP_INNER + dA] = __float2bfloat16(yo);      \
      }                                                                      \
      if (vB) {                                                              \
        float yo = (yB + xinS[trow + 2 * wid + 1] * dskB) * siluf(xzS[trow + 2 * wid + 1]); \
        ybf[(rb + (T0G) + brl) * KP_INNER + dB] = __float2bfloat16(yo);      \
      }                                                                      \
    }                                                                        \
  }

__global__ __launch_bounds__(512) void scan_fused(const uint* __restrict__ bcp16,
                                                  const float2* __restrict__ dtdu,
                                                  const __hip_bfloat16* __restrict__ xinbf,
                                                  const __hip_bfloat16* __restrict__ xzbf,
                                                  const float* __restrict__ A_log,
                                                  const float* __restrict__ Dskip,
                                                  __hip_bfloat16* __restrict__ ybf) {
  __shared__ __align__(16) float dts[2][16 * 68];
  __shared__ __align__(16) float dtus[2][16 * 68];
  __shared__ float xins[2][CHT * 17];
  __shared__ float xzs[2][CHT * 17];
  int tid = threadIdx.x, wid = tid >> 6, lane = tid & 63;
  int dg = blockIdx.x % DGRP, b = blockIdx.x / DGRP;
  int d0 = dg * 16;
  int dA = d0 + wid * 2, dB = dA + 1;
  bool vA = (dA < D_INNER), vB = (dB < D_INNER);
  int dcA = vA ? dA : (D_INNER - 1);
  int dcB = vB ? dB : (D_INNER - 1);
  const size_t rb = (size_t)b * T;

  auto stage = [&](int c, int s) {
#pragma unroll
    for (int j = 0; j < 2; ++j) {
      int t2 = tid + j * 512;
      int stt = t2 >> 4, sdd = t2 & 15;
      float2 dq = dtdu[(rb + c * CHT + stt) * D_INNER + d0 + sdd];
      dts[s][sdd * 68 + stt] = dq.x;
      dtus[s][sdd * 68 + stt] = dq.y;
      xins[s][stt * 17 + sdd] = __bfloat162float(xinbf[(rb + c * CHT + stt) * KP_INNER + d0 + sdd]);
      xzs[s][stt * 17 + sdd] = __bfloat162float(xzbf[(rb + c * CHT + stt) * D2 + D_INNER + d0 + sdd]);
    }
  };

  stage(0, 0);

  const bool bb2 = lane & 4, bb1 = lane & 2, bb0 = lane & 1;
  const int brl = ((lane & 1) << 2) | (lane & 2) | ((lane & 4) >> 2);
  float a2A = -__expf(A_log[(size_t)dcA * D_STATE + lane]) * 1.44269504f;
  float a2B = -__expf(A_log[(size_t)dcB * D_STATE + lane]) * 1.44269504f;
  float dskA = Dskip[dcA], dskB = Dskip[dcB];
  float hA = 0.f, hB = 0.f;
  const uint* bgp = bcp16 + rb * 64 + lane;

  __syncthreads();

  uint bA[8], bB[8];
#pragma unroll
  for (int k = 0; k < 8; ++k) bA[k] = bgp[k * 64];
  const uint* bq = bgp;  // pointer-bump: advances 1024 elems (16 t) per group

  for (int ch = 0; ch < NCH; ++ch) {
    int s = ch & 1;
    const float* dtsA = &dts[s][(2 * wid) * 68];
    const float* dtusA = &dtus[s][(2 * wid) * 68];
    const float* dtsB = &dts[s][(2 * wid + 1) * 68];
    const float* dtusB = &dtus[s][(2 * wid + 1) * 68];
    const float* xinS = &xins[s][0];
    const float* xzS = &xzs[s][0];
    if (ch + 1 < NCH) stage(ch + 1, s ^ 1);
#pragma unroll
    for (int gi = 0; gi < 4; ++gi) {
      int t0l = gi * 16;
      int t0g = ch * CHT + t0l;
#pragma unroll
      for (int k = 0; k < 8; ++k) bB[k] = bq[512 + k * 64];   // literal offsets 2048..3840B
      FCOMP2(bA, t0l, t0g);
      bq += 1024;
      if (!(ch == NCH - 1 && gi == 3)) {
#pragma unroll
        for (int k = 0; k < 8; ++k) bA[k] = bq[k * 64];       // literal offsets 0..1792B
      }
      FCOMP2(bB, t0l + 8, t0g + 8);
    }
    __syncthreads();
  }
}

// ---------------- launcher ----------------
extern "C" void kernel_launch(void* const* d_in, const int* in_sizes, int n_in,
                              void* d_out, int out_size, void* d_ws, size_t ws_size,
                              hipStream_t stream) {
  const float* x    = (const float*)d_in[0];
  const float* pcw  = (const float*)d_in[1];
  const float* pcb  = (const float*)d_in[2];
  const float* c1w  = (const float*)d_in[3];
  const float* c1b  = (const float*)d_in[4];
  const float* c2w  = (const float*)d_in[5];
  const float* c2b  = (const float*)d_in[6];
  const float* c3w  = (const float*)d_in[7];
  const float* c3b  = (const float*)d_in[8];
  const float* lnw  = (const float*)d_in[9];
  const float* lnb  = (const float*)d_in[10];
  const float* ow   = (const float*)d_in[11];
  const float* ob   = (const float*)d_in[12];
  const float* rmsw = (const float*)d_in[13];
  const float* Wi   = (const float*)d_in[14];
  const float* dww  = (const float*)d_in[15];
  const float* dwb  = (const float*)d_in[16];
  const float* Wx   = (const float*)d_in[17];
  const float* Wdt  = (const float*)d_in[18];
  const float* dtbv = (const float*)d_in[19];
  const float* Alog = (const float*)d_in[20];
  const float* Dsk  = (const float*)d_in[21];
  const float* Wo   = (const float*)d_in[22];
  float* out = (float*)d_out;

  char* w = (char*)d_ws;
  auto alloc = [&](size_t n) { char* p = w; w += (n + 255) & ~(size_t)255; return p; };
  // shared region: front-end buffers (dead after front GEMM) aliased with scan temps
  constexpr size_t REGION = 26400000;
  char* region = alloc(REGION);
  __hip_bfloat16* hpbfH = (__hip_bfloat16*)region;                   // 552,448 B (halo'd)
  __hip_bfloat16* Wfr  = (__hip_bfloat16*)(region + 14756096);       // 5,308,416 B
  float* cb768         = (float*)(region + 20065024);                // 3,072 B
  float2* dtduT        = (float2*)region;                            // 25,198,592 B (layer phase)
  __hip_bfloat16* bcbf = (__hip_bfloat16*)(region + 25198592);       // 524,288 B packed {B,C}

  float* hbuf          = (float*)alloc((size_t)BT * D_MODEL * 4);
  __hip_bfloat16* ubf  = (__hip_bfloat16*)alloc((size_t)BT * KP_MODEL * 2);
  __hip_bfloat16* xzbf = (__hip_bfloat16*)alloc((size_t)BT * D2 * 2);
  __hip_bfloat16* xinbf= (__hip_bfloat16*)alloc((size_t)BT * KP_INNER * 2);
  __hip_bfloat16* dtbf = (__hip_bfloat16*)alloc((size_t)BT * KP_DT * 2);
  __hip_bfloat16* ybf  = (__hip_bfloat16*)alloc((size_t)BT * KP_INNER * 2);
  __hip_bfloat16* Wibf = (__hip_bfloat16*)alloc((size_t)2 * NP_IN * KP_MODEL * 2);
  __hip_bfloat16* Wxbf = (__hip_bfloat16*)alloc((size_t)2 * NP_X * KP_INNER * 2);
  __hip_bfloat16* Wdtbf= (__hip_bfloat16*)alloc((size_t)2 * NP_DT * KP_DT * 2);
  __hip_bfloat16* Wobf = (__hip_bfloat16*)alloc((size_t)2 * NP_OUT * KP_INNER * 2);
  float* parts         = (float*)alloc((size_t)2 * BT * D_MODEL * 4);          // 12.6 MB split-K partials

  zero_halo<<<(B * 27 * 128 + 255) / 256, 256, 0, stream>>>(hpbfH);
  front_pointconv<<<dim3(T, B), 128, 0, stream>>>(x, pcw, pcb, hpbfH);
  build_conv_wb<<<2048, 256, 0, stream>>>(c1w, c2w, c3w, c1b, c2b, c3b, Wfr, cb768);
  cvt_all<<<dim3(1024, 8), 256, 0, stream>>>(Wi, Wx, Wdt, Wo, Wibf, Wxbf, Wdtbf, Wobf);
  gemm_bf16<6, 1><<<dim3(NCONV / 128, BT / 128, 2), 256, 0, stream>>>(
      hpbfH, Wfr, parts, BT, NCONV, KCONV, nullptr, 0, NCONV, nullptr, nullptr, nullptr);
  combine_conv_rms<<<BT, 256, 0, stream>>>(parts, cb768, x, rmsw, hbuf, ubf);
  // pad columns written once (scan/dwconv never touch cols >= D_INNER)
  zero_pad_cols<<<(BT * (KP_INNER - D_INNER) + 255) / 256, 256, 0, stream>>>(xinbf, BT, KP_INNER, D_INNER);
  zero_pad_cols<<<(BT * (KP_INNER - D_INNER) + 255) / 256, 256, 0, stream>>>(ybf, BT, KP_INNER, D_INNER);

  for (int l = 0; l < 2; ++l) {
    const float* Al = Alog + (size_t)l * D_INNER * D_STATE;
    gemm_bf16<7><<<dim3(NP_IN / 128, BT / 128), 256, 0, stream>>>(
        ubf, Wibf + (size_t)l * NP_IN * KP_MODEL, nullptr, BT, D2, KP_MODEL,
        nullptr, 0, D2, nullptr, xzbf, nullptr);
    dwconv_silu<<<(BT * 769 + 255) / 256, 256, 0, stream>>>(xzbf, dww + (size_t)l * D_INNER * 4,
                                                            dwb + (size_t)l * D_INNER, xinbf);
    gemm_bf16<6><<<dim3(NP_X / 128, BT / 128, 2), 256, 0, stream>>>(
        xinbf, Wxbf + (size_t)l * NP_X * KP_INNER, parts, BT,
        DT_RANK + 2 * D_STATE, KP_INNER, nullptr, 0, 256, nullptr, nullptr, nullptr);
    combine_xproj<<<(BT * 192 + 255) / 256, 256, 0, stream>>>(parts, dtbf, bcbf);
    gemm_bf16<1><<<dim3(NP_DT / 128, BT / 128), 256, 0, stream>>>(
        dtbf, Wdtbf + (size_t)l * NP_DT * KP_DT, nullptr, BT, D_INNER, KP_DT,
        dtbv + (size_t)l * D_INNER, 0, 0, dtduT, nullptr, xinbf);
    scan_fused<<<dim3(B * DGRP), 512, 0, stream>>>((const uint*)bcbf, dtduT, xinbf, xzbf, Al,
                                                   Dsk + (size_t)l * D_INNER, ybf);
    gemm_bf16<6><<<dim3(NP_OUT / 128, BT / 128, 2), 256, 0, stream>>>(
        ybf, Wobf + (size_t)l * NP_OUT * KP_INNER, parts, BT, D_MODEL, KP_INNER,
        nullptr, 0, D_MODEL, nullptr, nullptr, nullptr);
    if (l == 0) {
      combine_out_rms<<<BT, 256, 0, stream>>>(parts, rmsw + D_MODEL, hbuf, ubf);
    } else {
      combine_ln<<<BT, 256, 0, stream>>>(parts, hbuf, lnw, lnb, ow, ob, out);
    }
  }
}

// Round 19
// 469.343 us; speedup vs baseline: 1.1703x; 1.0106x over previous
//
#include <hip/hip_runtime.h>
#include <hip/hip_bf16.h>
#include <cstdint>
#include <math.h>

#define DEV static __device__ __forceinline__

typedef __attribute__((ext_vector_type(8))) __bf16 bf16x8v;
typedef __attribute__((ext_vector_type(4))) float f32x4;

constexpr int B = 4, T = 512, BT = B * T;
constexpr int D_MODEL = 769, D_INNER = 1538, D2 = 3076;
constexpr int DT_RANK = 49, D_STATE = 64;
constexpr int NCH = 8, CHT = 64;           // fused scan: 8 chunks x 64 t
constexpr int DGRP = (D_INNER + 15) / 16;  // 97 d-groups of 16
constexpr int THALO = 539;                 // 13 + 512 + 14 halo rows per b
// padded GEMM dims (K multiple of 64, N multiple of 128)
constexpr int KP_MODEL = 832;   // 769
constexpr int KP_INNER = 1600;  // 1538
constexpr int KP_DT    = 64;    // 49
constexpr int NP_IN  = 3200;    // 3076
constexpr int NP_X   = 256;     // 177
constexpr int NP_DT  = 1664;    // 1538
constexpr int NP_OUT = 896;     // 769
constexpr int KCONV  = 3456;    // 27*128 unified front-conv reduction
constexpr int NCONV  = 768;

DEV float fexp2(float x) { return __builtin_amdgcn_exp2f(x); }   // raw v_exp_f32
DEV float flog2(float x) { return __builtin_amdgcn_logf(x); }    // raw v_log_f32
DEV float frcp(float x) { return __builtin_amdgcn_rcpf(x); }     // raw v_rcp_f32
DEV float siluf(float v) { return v * frcp(1.f + fexp2(-1.44269504f * v)); }
DEV float softplusf(float v) {
  return fmaxf(v, 0.f) + 0.69314718f * flog2(1.f + fexp2(-1.44269504f * fabsf(v)));
}

DEV float wredx(float v) {
#pragma unroll
  for (int o = 1; o < 64; o <<= 1) v += __shfl_xor(v, o);
  return v;
}

// DPP / swizzle cross-lane helpers (VALU-pipe DPP where possible)
#define DPPF(v, ctrl) __uint_as_float((uint)__builtin_amdgcn_mov_dpp((int)__float_as_uint(v), (ctrl), 0xf, 0xf, true))
#define SWZF(v, pat) __uint_as_float((uint)__builtin_amdgcn_ds_swizzle((int)__float_as_uint(v), (pat)))

DEV void gload_lds16(const void* g, void* l) {
  __builtin_amdgcn_global_load_lds(
      (const __attribute__((address_space(1))) uint32_t*)(uintptr_t)g,
      (__attribute__((address_space(3))) uint32_t*)(uint32_t)(uintptr_t)l,
      16, 0, 0);
}

// ---------------- front end ----------------

// x (B,T,65) -> hpbfH (B,539,128) halo'd, rows 13..524 = silu(pointconv)
__global__ void front_pointconv(const float* __restrict__ x, const float* __restrict__ pw,
                                const float* __restrict__ pb, __hip_bfloat16* __restrict__ hpbfH) {
  int t = blockIdx.x, b = blockIdx.y, c = threadIdx.x;  // 128 threads
  __shared__ float xs[64];
  if (c < 64) xs[c] = x[((size_t)b * T + t) * 65 + c];
  __syncthreads();
  float acc = pb[c];
  const float4* pwr = (const float4*)(pw + c * 64);
#pragma unroll
  for (int i = 0; i < 16; ++i) {
    float4 w4 = pwr[i];
    acc = fmaf(w4.x, xs[4 * i + 0], acc);
    acc = fmaf(w4.y, xs[4 * i + 1], acc);
    acc = fmaf(w4.z, xs[4 * i + 2], acc);
    acc = fmaf(w4.w, xs[4 * i + 3], acc);
  }
  hpbfH[((size_t)b * THALO + 13 + t) * 128 + c] = __float2bfloat16(siluf(acc));
}

// zero halo rows 0..12 and 525..538 of each b
__global__ void zero_halo(__hip_bfloat16* __restrict__ h) {
  int i = blockIdx.x * 256 + threadIdx.x;
  if (i >= B * 27 * 128) return;
  int b = i / (27 * 128), r = i - b * 27 * 128;
  int row = r >> 7, c = r & 127;
  int rr = (row < 13) ? row : row + 512;
  h[((size_t)b * THALO + rr) * 128 + c] = __float2bfloat16(0.f);
}

// c1w/c2w/c3w -> Wfr(768, 3456) bf16; tail range fills bias vector
__global__ void build_conv_wb(const float* __restrict__ c1w, const float* __restrict__ c2w,
                              const float* __restrict__ c3w, const float* __restrict__ b1,
                              const float* __restrict__ b2, const float* __restrict__ b3,
                              __hip_bfloat16* __restrict__ Wfr, float* __restrict__ cb) {
  int total = NCONV * KCONV;
  for (int idx = blockIdx.x * 256 + threadIdx.x; idx < total + NCONV; idx += gridDim.x * 256) {
    if (idx < total) {
      int co = idx / KCONV, r = idx - co * KCONV;
      int j = r >> 7, ci = r & 127;
      float v = 0.f;
      if (co < 256) {
        int k = j - 12;
        if (k >= 0 && k < 3) v = c1w[((size_t)co * 128 + ci) * 3 + k];
      } else if (co < 512) {
        int k = j - 9;
        if (k >= 0 && k < 9) v = c2w[((size_t)(co - 256) * 128 + ci) * 9 + k];
      } else {
        v = c3w[((size_t)(co - 512) * 128 + ci) * 27 + j];
      }
      Wfr[idx] = __float2bfloat16(v);
    } else {
      int i = idx - total;
      cb[i] = (i < 256) ? b1[i] : (i < 512) ? b2[i - 256] : b3[i - 512];
    }
  }
}

// ---------------- weight conversion, all tensors both layers, 1 launch ----------------
__global__ void cvt_all(const float* __restrict__ Wi, const float* __restrict__ Wx,
                        const float* __restrict__ Wdt, const float* __restrict__ Wo,
                        __hip_bfloat16* __restrict__ Wibf, __hip_bfloat16* __restrict__ Wxbf,
                        __hip_bfloat16* __restrict__ Wdtbf, __hip_bfloat16* __restrict__ Wobf) {
  int l = blockIdx.y >> 2, t = blockIdx.y & 3;
  const float* src;
  __hip_bfloat16* dst;
  int N, K, Npad, Kpad;
  if (t == 0) { src = Wi + (size_t)l * D2 * D_MODEL; dst = Wibf + (size_t)l * NP_IN * KP_MODEL;
                N = D2; K = D_MODEL; Npad = NP_IN; Kpad = KP_MODEL; }
  else if (t == 1) { src = Wx + (size_t)l * (DT_RANK + 2 * D_STATE) * D_INNER;
                dst = Wxbf + (size_t)l * NP_X * KP_INNER;
                N = DT_RANK + 2 * D_STATE; K = D_INNER; Npad = NP_X; Kpad = KP_INNER; }
  else if (t == 2) { src = Wdt + (size_t)l * D_INNER * DT_RANK; dst = Wdtbf + (size_t)l * NP_DT * KP_DT;
                N = D_INNER; K = DT_RANK; Npad = NP_DT; Kpad = KP_DT; }
  else { src = Wo + (size_t)l * D_MODEL * D_INNER; dst = Wobf + (size_t)l * NP_OUT * KP_INNER;
                N = D_MODEL; K = D_INNER; Npad = NP_OUT; Kpad = KP_INNER; }
  int total = Npad * Kpad;
  for (int idx = blockIdx.x * 256 + threadIdx.x; idx < total; idx += gridDim.x * 256) {
    int n = idx / Kpad, k = idx - n * Kpad;
    float v = (n < N && k < K) ? src[(size_t)n * K + k] : 0.f;
    dst[idx] = __float2bfloat16(v);
  }
}

__global__ void zero_pad_cols(__hip_bfloat16* __restrict__ buf, int rows, int ld, int c0) {
  int w = ld - c0;
  int total = rows * w;
  int idx = blockIdx.x * 256 + threadIdx.x;
  if (idx < total) buf[(size_t)(idx / w) * ld + c0 + (idx % w)] = __float2bfloat16(0.f);
}

// ---------------- bf16 MFMA GEMM:  C[m][n] = sum_k A[m][k] * W[n][k] (+ epilogue) ----------------
// EPI 1: softplus(acc+bias[n]) -> packed bf16x2 {dt, dt*du} uint in (b,t,d);
// 6: split-K raw partial store; 7: bf16 store to auxb[m*ldc+n]
// CONV=1: A is halo'd hpbfH with row stride 256B (im2col-free front conv).
// XCD-aware swizzle: weight-panel-major chunking so each XCD touches few N-panels.
template <int EPI, int CONV = 0>
__global__ __launch_bounds__(256) void gemm_bf16(const __hip_bfloat16* __restrict__ A,
                                                 const __hip_bfloat16* __restrict__ W,
                                                 float* __restrict__ C, int M, int Nreal, int Kp,
                                                 const float* extra, int ldadd, int ldc,
                                                 uint* auxv, __hip_bfloat16* auxb,
                                                 const __hip_bfloat16* auxr) {
  __shared__ __align__(16) __hip_bfloat16 As[128 * 64];
  __shared__ __align__(16) __hip_bfloat16 Bs[128 * 64];
  const int tid = threadIdx.x;
  const int wid = tid >> 6, lane = tid & 63;
  const int wr = wid >> 1, wc = wid & 1;
  int bx = blockIdx.x, by = blockIdx.y;
  {
    int gx = gridDim.x, gy = gridDim.y;
    int nwg = gx * gy;
    if ((nwg & 7) == 0) {
      int hid = by * gx + bx;                 // hw dispatch linear id (x fastest)
      int wkl = (hid & 7) * (nwg >> 3) + (hid >> 3);  // XCD k owns contiguous chunk
      bx = wkl / gy;                          // column-major: chunk = few bx (weight panels)
      by = wkl - bx * gy;
    }
  }
  const int m0 = by * 128, n0 = bx * 128;
  f32x4 acc[4][4] = {};
  const int lrow = lane >> 3;                                 // row within 8-row segment
  const int cbyte = ((lane & 7) << 4) ^ (lrow << 4);          // inverse-swizzled source col byte
  const char* Wb = (const char*)W;
  const size_t strideB = (size_t)Kp * 2;
  const char* ArowBase;
  size_t sA;
  if constexpr (CONV) {
    int brow = m0 >> 9;
    ArowBase = (const char*)A + (size_t)(brow * THALO + (m0 & 511)) * 256;
    sA = 256;
  } else {
    ArowBase = (const char*)A + (size_t)m0 * strideB;
    sA = strideB;
  }
  const int swz = (lane & 7) << 4;

  int kbeg = 0, kend = Kp;
  if constexpr (EPI == 6) {
    int khalf = (((Kp >> 1) + 63) >> 6) << 6;
    if (blockIdx.z == 0) kend = khalf; else kbeg = khalf;
  }

  for (int k0 = kbeg; k0 < kend; k0 += 64) {
#pragma unroll
    for (int i = 0; i < 4; ++i) {
      int seg = i * 4 + wid;                                  // wave-uniform
      int row = seg * 8 + lrow;
      gload_lds16(ArowBase + (size_t)row * sA + k0 * 2 + cbyte, (char*)As + seg * 1024);
      gload_lds16(Wb + (size_t)(n0 + row) * strideB + k0 * 2 + cbyte, (char*)Bs + seg * 1024);
    }
    __syncthreads();
#pragma unroll
    for (int kk = 0; kk < 2; ++kk) {
      int kb = kk * 64 + ((lane >> 4) << 4);                  // byte offset of this lane's 8 bf16
      bf16x8v af[4], bfr[4];
#pragma unroll
      for (int mi = 0; mi < 4; ++mi) {
        int row = wr * 64 + mi * 16 + (lane & 15);
        af[mi] = *(const bf16x8v*)((const char*)As + row * 128 + (kb ^ swz));
      }
#pragma unroll
      for (int ni = 0; ni < 4; ++ni) {
        int row = wc * 64 + ni * 16 + (lane & 15);
        bfr[ni] = *(const bf16x8v*)((const char*)Bs + row * 128 + (kb ^ swz));
      }
#pragma unroll
      for (int mi = 0; mi < 4; ++mi)
#pragma unroll
        for (int ni = 0; ni < 4; ++ni)
          acc[mi][ni] = __builtin_amdgcn_mfma_f32_16x16x32_bf16(af[mi], bfr[ni], acc[mi][ni], 0, 0, 0);
    }
    __syncthreads();
  }

#pragma unroll
  for (int mi = 0; mi < 4; ++mi) {
#pragma unroll
    for (int ni = 0; ni < 4; ++ni) {
      int n = n0 + wc * 64 + ni * 16 + (lane & 15);
      if (n < Nreal) {
        int mb = m0 + wr * 64 + mi * 16 + ((lane >> 4) << 2);
#pragma unroll
        for (int v = 0; v < 4; ++v) {
          float val = acc[mi][ni][v];
          int m = mb + v;
          if constexpr (EPI == 1) {
            float dt = softplusf(val + extra[n]);
            float du = __bfloat162float(auxr[(size_t)m * KP_INNER + n]);
            uint lo = (__float_as_uint(dt) + 0x8000u) >> 16;
            uint hi = (__float_as_uint(dt * du) + 0x8000u) & 0xffff0000u;
            auxv[(size_t)m * D_INNER + n] = lo | hi;   // packed {dt, dt*du}, coalesced
          } else if constexpr (EPI == 6) {
            C[((size_t)blockIdx.z * M + m) * ldc + n] = val;
          } else if constexpr (EPI == 7) {
            auxb[(size_t)m * ldc + n] = __float2bfloat16(val);
          } else {
            C[(size_t)m * ldc + n] = val;
          }
        }
      }
    }
  }
}

// ---------------- fused combine kernels (block per row) ----------------
// front conv combine + silu + pe + rmsnorm -> hbuf, ubf
__global__ __launch_bounds__(256) void combine_conv_rms(const float* __restrict__ p,
                                                        const float* __restrict__ cb,
                                                        const float* __restrict__ x,
                                                        const float* __restrict__ rmsw,
                                                        float* __restrict__ h,
                                                        __hip_bfloat16* __restrict__ ubf) {
  int m = blockIdx.x;
  __shared__ float sh[D_MODEL];
  __shared__ float red[4];
  int wid = threadIdx.x >> 6, lane = threadIdx.x & 63;
  float ss = 0.f;
  for (int n = threadIdx.x; n < D_MODEL; n += 256) {
    float v;
    if (n < NCONV)
      v = siluf(p[(size_t)m * NCONV + n] + p[(size_t)BT * NCONV + (size_t)m * NCONV + n] + cb[n]);
    else
      v = x[(size_t)m * 65 + 64];
    sh[n] = v;
    h[(size_t)m * D_MODEL + n] = v;
    ss = fmaf(v, v, ss);
  }
  ss = wredx(ss);
  if (lane == 0) red[wid] = ss;
  __syncthreads();
  float sc = rsqrtf((red[0] + red[1] + red[2] + red[3]) * (1.f / D_MODEL) + 1e-6f);
  for (int i = threadIdx.x; i < KP_MODEL; i += 256) {
    float v = (i < D_MODEL) ? sh[i] * sc * rmsw[i] : 0.f;
    ubf[(size_t)m * KP_MODEL + i] = __float2bfloat16(v);
  }
}

// out_proj combine + residual + rmsnorm(next layer) -> hbuf, ubf
__global__ __launch_bounds__(256) void combine_out_rms(const float* __restrict__ p,
                                                       const float* __restrict__ rmsw,
                                                       float* __restrict__ h,
                                                       __hip_bfloat16* __restrict__ ubf) {
  int m = blockIdx.x;
  __shared__ float sh[D_MODEL];
  __shared__ float red[4];
  int wid = threadIdx.x >> 6, lane = threadIdx.x & 63;
  float ss = 0.f;
  for (int n = threadIdx.x; n < D_MODEL; n += 256) {
    size_t i = (size_t)m * D_MODEL + n;
    float v = h[i] + p[i] + p[(size_t)BT * D_MODEL + i];
    sh[n] = v;
    h[i] = v;
    ss = fmaf(v, v, ss);
  }
  ss = wredx(ss);
  if (lane == 0) red[wid] = ss;
  __syncthreads();
  float sc = rsqrtf((red[0] + red[1] + red[2] + red[3]) * (1.f / D_MODEL) + 1e-6f);
  for (int i = threadIdx.x; i < KP_MODEL; i += 256) {
    float v = (i < D_MODEL) ? sh[i] * sc * rmsw[i] : 0.f;
    ubf[(size_t)m * KP_MODEL + i] = __float2bfloat16(v);
  }
}

// last layer: out_proj combine + residual + layernorm + classifier head -> out
__global__ __launch_bounds__(256) void combine_ln(const float* __restrict__ p,
                                                  const float* __restrict__ h,
                                                  const float* __restrict__ lnw,
                                                  const float* __restrict__ lnb,
                                                  const float* __restrict__ ow,
                                                  const float* __restrict__ ob,
                                                  float* __restrict__ out) {
  int row = blockIdx.x;
  __shared__ float sh[D_MODEL];
  __shared__ float red[4];
  int wid = threadIdx.x >> 6, lane = threadIdx.x & 63;
  float s = 0.f;
  for (int i = threadIdx.x; i < D_MODEL; i += 256) {
    size_t ix = (size_t)row * D_MODEL + i;
    float v = h[ix] + p[ix] + p[(size_t)BT * D_MODEL + ix];
    sh[i] = v;
    s += v;
  }
  s = wredx(s);
  if (lane == 0) red[wid] = s;
  __syncthreads();
  float mean = (red[0] + red[1] + red[2] + red[3]) * (1.f / D_MODEL);
  __syncthreads();
  float vs = 0.f;
  for (int i = threadIdx.x; i < D_MODEL; i += 256) { float dd = sh[i] - mean; vs = fmaf(dd, dd, vs); }
  vs = wredx(vs);
  if (lane == 0) red[wid] = vs;
  __syncthreads();
  float var = (red[0] + red[1] + red[2] + red[3]) * (1.f / D_MODEL);
  float inv = rsqrtf(var + 1e-5f);
  for (int i = threadIdx.x; i < D_MODEL; i += 256)
    sh[i] = (sh[i] - mean) * inv * lnw[i] + lnb[i];
  __syncthreads();
  for (int c = wid; c < 10; c += 4) {
    float acc = 0.f;
    for (int i = lane; i < D_MODEL; i += 64) acc = fmaf(sh[i], ow[(size_t)c * D_MODEL + i], acc);
    acc = wredx(acc);
    if (lane == 0) out[(size_t)row * 10 + c] = acc + ob[c];
  }
}

// x_proj combine: parts (2, BT, 256) -> dtbf (BT,64) bf16 + bcbf (BT,64) packed {B,C} bf16x2
__global__ void combine_xproj(const float* __restrict__ p, __hip_bfloat16* __restrict__ dtbf,
                              __hip_bfloat16* __restrict__ bcb) {
  int i = blockIdx.x * 256 + threadIdx.x;
  if (i >= BT * 192) return;
  int m = i / 192, n = i - m * 192;
  if (n >= DT_RANK + 2 * D_STATE) return;
  float v = p[(size_t)m * 256 + n] + p[(size_t)(BT + m) * 256 + n];
  if (n < 64) dtbf[(size_t)m * 64 + n] = __float2bfloat16(n < DT_RANK ? v : 0.f);
  if (n >= DT_RANK && n < DT_RANK + D_STATE)
    bcb[((size_t)m * 64 + (n - DT_RANK)) * 2] = __float2bfloat16(v);          // B -> lo
  else if (n >= DT_RANK + D_STATE)
    bcb[((size_t)m * 64 + (n - DT_RANK - D_STATE)) * 2 + 1] = __float2bfloat16(v);  // C -> hi
}

// ---------------- depthwise causal conv (k=4) + silu, 2 d per thread (packed) ----------------
__global__ void dwconv_silu(const __hip_bfloat16* __restrict__ xz, const float* __restrict__ cw,
                            const float* __restrict__ cb, __hip_bfloat16* __restrict__ xinbf) {
  int idx = blockIdx.x * 256 + threadIdx.x;
  if (idx >= BT * 769) return;                 // D_INNER/2 pairs
  int bt = idx / 769;
  int dd = idx - bt * 769;                     // pair index; d = 2*dd, d+1
  int d = dd * 2;
  int t = bt & (T - 1);
  float4 w0 = *(const float4*)(cw + (size_t)d * 4);
  float4 w1 = *(const float4*)(cw + (size_t)(d + 1) * 4);
  float acc0 = cb[d], acc1 = cb[d + 1];
  const uint* col = (const uint*)(xz + (size_t)bt * D2) + dd;
  float wk0[4] = {w0.x, w0.y, w0.z, w0.w};
  float wk1[4] = {w1.x, w1.y, w1.z, w1.w};
#pragma unroll
  for (int k = 0; k < 4; ++k) {
    int tt = t + k - 3;
    uint v = (tt >= 0) ? col[(ptrdiff_t)(k - 3) * (D2 / 2)] : 0u;
    float lo = __uint_as_float(v << 16);
    float hi = __uint_as_float(v & 0xffff0000u);
    acc0 = fmaf(wk0[k], lo, acc0);
    acc1 = fmaf(wk1[k], hi, acc1);
  }
  acc0 = siluf(acc0);
  acc1 = siluf(acc1);
  uint lo16 = (__float_as_uint(acc0) + 0x8000u) >> 16;   // RTN-ish bf16 pack
  uint hi16 = (__float_as_uint(acc1) + 0x8000u) & 0xffff0000u;
  ((uint*)xinbf)[(size_t)bt * (KP_INNER / 2) + dd] = lo16 | hi16;
}

// ---------------- fused single-pass scan: 512 threads, 8 waves x 2 d/wave, 16 d/block ----------------
// r16 config (measured optimum of 16d/512t=104, 8d/256t=108, 12d/384t=145 µs).
// dtdu now packed bf16x2 in global; unpacked to f32 in stage() (off the hot path).
// Each wave carries TWO independent h chains; LDS staging double-buffered per 64-t chunk;
// bc via register ping-pong with pointer-bump literal offsets. Reduce: DPP + 3 DS ops.

#define FCOMP2(REG, T0L, T0G)                                                \
  {                                                                          \
    float4 qa0 = *(const float4*)&dtsA[(T0L)];                               \
    float4 qa1 = *(const float4*)&dtsA[(T0L) + 4];                           \
    float4 ua0 = *(const float4*)&dtusA[(T0L)];                              \
    float4 ua1 = *(const float4*)&dtusA[(T0L) + 4];                          \
    float4 qb0 = *(const float4*)&dtsB[(T0L)];                               \
    float4 qb1 = *(const float4*)&dtsB[(T0L) + 4];                           \
    float4 ub0 = *(const float4*)&dtusB[(T0L)];                              \
    float4 ub1 = *(const float4*)&dtusB[(T0L) + 4];                          \
    float dtvA[8] = {qa0.x, qa0.y, qa0.z, qa0.w, qa1.x, qa1.y, qa1.z, qa1.w};\
    float duvA[8] = {ua0.x, ua0.y, ua0.z, ua0.w, ua1.x, ua1.y, ua1.z, ua1.w};\
    float dtvB[8] = {qb0.x, qb0.y, qb0.z, qb0.w, qb1.x, qb1.y, qb1.z, qb1.w};\
    float duvB[8] = {ub0.x, ub0.y, ub0.z, ub0.w, ub1.x, ub1.y, ub1.z, ub1.w};\
    float vvA[8], vvB[8];                                                    \
    _Pragma("unroll") for (int k = 0; k < 8; ++k) {                          \
      float Bv = __uint_as_float(REG[k] << 16);                              \
      float Cv = __uint_as_float(REG[k] & 0xffff0000u);                      \
      hA = fmaf(fexp2(dtvA[k] * a2A), hA, duvA[k] * Bv);                     \
      hB = fmaf(fexp2(dtvB[k] * a2B), hB, duvB[k] * Bv);                     \
      vvA[k] = hA * Cv;                                                      \
      vvB[k] = hB * Cv;                                                      \
    }                                                                        \
    _Pragma("unroll") for (int k = 0; k < 4; ++k) {                          \
      float sA = bb0 ? vvA[k] : vvA[k + 4];                                  \
      float kA = bb0 ? vvA[k + 4] : vvA[k];                                  \
      vvA[k] = kA + DPPF(sA, 0xB1);                                          \
      float sB = bb0 ? vvB[k] : vvB[k + 4];                                  \
      float kB = bb0 ? vvB[k + 4] : vvB[k];                                  \
      vvB[k] = kB + DPPF(sB, 0xB1);                                          \
    }                                                                        \
    _Pragma("unroll") for (int k = 0; k < 2; ++k) {                          \
      float sA = bb1 ? vvA[k] : vvA[k + 2];                                  \
      float kA = bb1 ? vvA[k + 2] : vvA[k];                                  \
      vvA[k] = kA + DPPF(sA, 0x4E);                                          \
      float sB = bb1 ? vvB[k] : vvB[k + 2];                                  \
      float kB = bb1 ? vvB[k + 2] : vvB[k];                                  \
      vvB[k] = kB + DPPF(sB, 0x4E);                                          \
    }                                                                        \
    {                                                                        \
      float sA = bb2 ? vvA[0] : vvA[1];                                      \
      float kA = bb2 ? vvA[1] : vvA[0];                                      \
      vvA[0] = kA + SWZF(sA, 0x101F);                                        \
      float sB = bb2 ? vvB[0] : vvB[1];                                      \
      float kB = bb2 ? vvB[1] : vvB[0];                                      \
      vvB[0] = kB + SWZF(sB, 0x101F);                                        \
    }                                                                        \
    float yA = vvA[0], yB = vvB[0];                                          \
    yA += DPPF(yA, 0x128);  yB += DPPF(yB, 0x128);                           \
    yA += SWZF(yA, 0x401F); yB += SWZF(yB, 0x401F);                          \
    yA += __shfl_xor(yA, 32); yB += __shfl_xor(yB, 32);                      \
    if (lane < 8) {                                                          \
      int trow = ((T0L) + brl) * 17;                                         \
      if (vA) {                                                              \
        float yo = (yA + xinS[trow + 2 * wid] * dskA) * siluf(xzS[trow + 2 * wid]); \
        ybf[(rb + (T0G) + brl) * KP_INNER + dA] = __float2bfloat16(yo);      \
      }                                                                      \
      if (vB) {                                                              \
        float yo = (yB + xinS[trow + 2 * wid + 1] * dskB) * siluf(xzS[trow + 2 * wid + 1]); \
        ybf[(rb + (T0G) + brl) * KP_INNER + dB] = __float2bfloat16(yo);      \
      }                                                                      \
    }                                                                        \
  }

__global__ __launch_bounds__(512) void scan_fused(const uint* __restrict__ bcp16,
                                                  const uint* __restrict__ dtduP,
                                                  const __hip_bfloat16* __restrict__ xinbf,
                                                  const __hip_bfloat16* __restrict__ xzbf,
                                                  const float* __restrict__ A_log,
                                                  const float* __restrict__ Dskip,
                                                  __hip_bfloat16* __restrict__ ybf) {
  __shared__ __align__(16) float dts[2][16 * 68];
  __shared__ __align__(16) float dtus[2][16 * 68];
  __shared__ float xins[2][CHT * 17];
  __shared__ float xzs[2][CHT * 17];
  int tid = threadIdx.x, wid = tid >> 6, lane = tid & 63;
  int dg = blockIdx.x % DGRP, b = blockIdx.x / DGRP;
  int d0 = dg * 16;
  int dA = d0 + wid * 2, dB = dA + 1;
  bool vA = (dA < D_INNER), vB = (dB < D_INNER);
  int dcA = vA ? dA : (D_INNER - 1);
  int dcB = vB ? dB : (D_INNER - 1);
  const size_t rb = (size_t)b * T;

  auto stage = [&](int c, int s) {
#pragma unroll
    for (int j = 0; j < 2; ++j) {
      int t2 = tid + j * 512;
      int stt = t2 >> 4, sdd = t2 & 15;
      uint dq = dtduP[(rb + c * CHT + stt) * D_INNER + d0 + sdd];
      dts[s][sdd * 68 + stt] = __uint_as_float(dq << 16);
      dtus[s][sdd * 68 + stt] = __uint_as_float(dq & 0xffff0000u);
      xins[s][stt * 17 + sdd] = __bfloat162float(xinbf[(rb + c * CHT + stt) * KP_INNER + d0 + sdd]);
      xzs[s][stt * 17 + sdd] = __bfloat162float(xzbf[(rb + c * CHT + stt) * D2 + D_INNER + d0 + sdd]);
    }
  };

  stage(0, 0);

  const bool bb2 = lane & 4, bb1 = lane & 2, bb0 = lane & 1;
  const int brl = ((lane & 1) << 2) | (lane & 2) | ((lane & 4) >> 2);
  float a2A = -__expf(A_log[(size_t)dcA * D_STATE + lane]) * 1.44269504f;
  float a2B = -__expf(A_log[(size_t)dcB * D_STATE + lane]) * 1.44269504f;
  float dskA = Dskip[dcA], dskB = Dskip[dcB];
  float hA = 0.f, hB = 0.f;
  const uint* bgp = bcp16 + rb * 64 + lane;

  __syncthreads();

  uint bA[8], bB[8];
#pragma unroll
  for (int k = 0; k < 8; ++k) bA[k] = bgp[k * 64];
  const uint* bq = bgp;  // pointer-bump: advances 1024 elems (16 t) per group

  for (int ch = 0; ch < NCH; ++ch) {
    int s = ch & 1;
    const float* dtsA = &dts[s][(2 * wid) * 68];
    const float* dtusA = &dtus[s][(2 * wid) * 68];
    const float* dtsB = &dts[s][(2 * wid + 1) * 68];
    const float* dtusB = &dtus[s][(2 * wid + 1) * 68];
    const float* xinS = &xins[s][0];
    const float* xzS = &xzs[s][0];
    if (ch + 1 < NCH) stage(ch + 1, s ^ 1);
#pragma unroll
    for (int gi = 0; gi < 4; ++gi) {
      int t0l = gi * 16;
      int t0g = ch * CHT + t0l;
#pragma unroll
      for (int k = 0; k < 8; ++k) bB[k] = bq[512 + k * 64];   // literal offsets 2048..3840B
      FCOMP2(bA, t0l, t0g);
      bq += 1024;
      if (!(ch == NCH - 1 && gi == 3)) {
#pragma unroll
        for (int k = 0; k < 8; ++k) bA[k] = bq[k * 64];       // literal offsets 0..1792B
      }
      FCOMP2(bB, t0l + 8, t0g + 8);
    }
    __syncthreads();
  }
}

// ---------------- launcher ----------------
extern "C" void kernel_launch(void* const* d_in, const int* in_sizes, int n_in,
                              void* d_out, int out_size, void* d_ws, size_t ws_size,
                              hipStream_t stream) {
  const float* x    = (const float*)d_in[0];
  const float* pcw  = (const float*)d_in[1];
  const float* pcb  = (const float*)d_in[2];
  const float* c1w  = (const float*)d_in[3];
  const float* c1b  = (const float*)d_in[4];
  const float* c2w  = (const float*)d_in[5];
  const float* c2b  = (const float*)d_in[6];
  const float* c3w  = (const float*)d_in[7];
  const float* c3b  = (const float*)d_in[8];
  const float* lnw  = (const float*)d_in[9];
  const float* lnb  = (const float*)d_in[10];
  const float* ow   = (const float*)d_in[11];
  const float* ob   = (const float*)d_in[12];
  const float* rmsw = (const float*)d_in[13];
  const float* Wi   = (const float*)d_in[14];
  const float* dww  = (const float*)d_in[15];
  const float* dwb  = (const float*)d_in[16];
  const float* Wx   = (const float*)d_in[17];
  const float* Wdt  = (const float*)d_in[18];
  const float* dtbv = (const float*)d_in[19];
  const float* Alog = (const float*)d_in[20];
  const float* Dsk  = (const float*)d_in[21];
  const float* Wo   = (const float*)d_in[22];
  float* out = (float*)d_out;

  char* w = (char*)d_ws;
  auto alloc = [&](size_t n) { char* p = w; w += (n + 255) & ~(size_t)255; return p; };
  // shared region: front-end buffers (dead after front GEMM) aliased with scan temps
  constexpr size_t REGION = 26400000;
  char* region = alloc(REGION);
  __hip_bfloat16* hpbfH = (__hip_bfloat16*)region;                   // 552,448 B (halo'd)
  __hip_bfloat16* Wfr  = (__hip_bfloat16*)(region + 14756096);       // 5,308,416 B
  float* cb768         = (float*)(region + 20065024);                // 3,072 B
  uint* dtduP          = (uint*)region;                              // 12,599,296 B (layer phase)
  __hip_bfloat16* bcbf = (__hip_bfloat16*)(region + 25198592);       // 524,288 B packed {B,C}

  float* hbuf          = (float*)alloc((size_t)BT * D_MODEL * 4);
  __hip_bfloat16* ubf  = (__hip_bfloat16*)alloc((size_t)BT * KP_MODEL * 2);
  __hip_bfloat16* xzbf = (__hip_bfloat16*)alloc((size_t)BT * D2 * 2);
  __hip_bfloat16* xinbf= (__hip_bfloat16*)alloc((size_t)BT * KP_INNER * 2);
  __hip_bfloat16* dtbf = (__hip_bfloat16*)alloc((size_t)BT * KP_DT * 2);
  __hip_bfloat16* ybf  = (__hip_bfloat16*)alloc((size_t)BT * KP_INNER * 2);
  __hip_bfloat16* Wibf = (__hip_bfloat16*)alloc((size_t)2 * NP_IN * KP_MODEL * 2);
  __hip_bfloat16* Wxbf = (__hip_bfloat16*)alloc((size_t)2 * NP_X * KP_INNER * 2);
  __hip_bfloat16* Wdtbf= (__hip_bfloat16*)alloc((size_t)2 * NP_DT * KP_DT * 2);
  __hip_bfloat16* Wobf = (__hip_bfloat16*)alloc((size_t)2 * NP_OUT * KP_INNER * 2);
  float* parts         = (float*)alloc((size_t)2 * BT * D_MODEL * 4);          // 12.6 MB split-K partials

  zero_halo<<<(B * 27 * 128 + 255) / 256, 256, 0, stream>>>(hpbfH);
  front_pointconv<<<dim3(T, B), 128, 0, stream>>>(x, pcw, pcb, hpbfH);
  build_conv_wb<<<2048, 256, 0, stream>>>(c1w, c2w, c3w, c1b, c2b, c3b, Wfr, cb768);
  cvt_all<<<dim3(1024, 8), 256, 0, stream>>>(Wi, Wx, Wdt, Wo, Wibf, Wxbf, Wdtbf, Wobf);
  gemm_bf16<6, 1><<<dim3(NCONV / 128, BT / 128, 2), 256, 0, stream>>>(
      hpbfH, Wfr, parts, BT, NCONV, KCONV, nullptr, 0, NCONV, nullptr, nullptr, nullptr);
  combine_conv_rms<<<BT, 256, 0, stream>>>(parts, cb768, x, rmsw, hbuf, ubf);
  // pad columns written once (scan/dwconv never touch cols >= D_INNER)
  zero_pad_cols<<<(BT * (KP_INNER - D_INNER) + 255) / 256, 256, 0, stream>>>(xinbf, BT, KP_INNER, D_INNER);
  zero_pad_cols<<<(BT * (KP_INNER - D_INNER) + 255) / 256, 256, 0, stream>>>(ybf, BT, KP_INNER, D_INNER);

  for (int l = 0; l < 2; ++l) {
    const float* Al = Alog + (size_t)l * D_INNER * D_STATE;
    gemm_bf16<7><<<dim3(NP_IN / 128, BT / 128), 256, 0, stream>>>(
        ubf, Wibf + (size_t)l * NP_IN * KP_MODEL, nullptr, BT, D2, KP_MODEL,
        nullptr, 0, D2, nullptr, xzbf, nullptr);
    dwconv_silu<<<(BT * 769 + 255) / 256, 256, 0, stream>>>(xzbf, dww + (size_t)l * D_INNER * 4,
                                                            dwb + (size_t)l * D_INNER, xinbf);
    gemm_bf16<6><<<dim3(NP_X / 128, BT / 128, 2), 256, 0, stream>>>(
        xinbf, Wxbf + (size_t)l * NP_X * KP_INNER, parts, BT,
        DT_RANK + 2 * D_STATE, KP_INNER, nullptr, 0, 256, nullptr, nullptr, nullptr);
    combine_xproj<<<(BT * 192 + 255) / 256, 256, 0, stream>>>(parts, dtbf, bcbf);
    gemm_bf16<1><<<dim3(NP_DT / 128, BT / 128), 256, 0, stream>>>(
        dtbf, Wdtbf + (size_t)l * NP_DT * KP_DT, nullptr, BT, D_INNER, KP_DT,
        dtbv + (size_t)l * D_INNER, 0, 0, dtduP, nullptr, xinbf);
    scan_fused<<<dim3(B * DGRP), 512, 0, stream>>>((const uint*)bcbf, dtduP, xinbf, xzbf, Al,
                                                   Dsk + (size_t)l * D_INNER, ybf);
    gemm_bf16<6><<<dim3(NP_OUT / 128, BT / 128, 2), 256, 0, stream>>>(
        ybf, Wobf + (size_t)l * NP_OUT * KP_INNER, parts, BT, D_MODEL, KP_INNER,
        nullptr, 0, D_MODEL, nullptr, nullptr, nullptr);
    if (l == 0) {
      combine_out_rms<<<BT, 256, 0, stream>>>(parts, rmsw + D_MODEL, hbuf, ubf);
    } else {
      combine_ln<<<BT, 256, 0, stream>>>(parts, hbuf, lnw, lnb, ow, ob, out);
    }
  }
}

// Round 20
// 439.251 us; speedup vs baseline: 1.2505x; 1.0685x over previous
//
#include <hip/hip_runtime.h>
#include <hip/hip_bf16.h>
#include <cstdint>
#include <math.h>

#define DEV static __device__ __forceinline__

typedef __attribute__((ext_vector_type(8))) __bf16 bf16x8v;
typedef __attribute__((ext_vector_type(4))) float f32x4;

constexpr int B = 4, T = 512, BT = B * T;
constexpr int D_MODEL = 769, D_INNER = 1538, D2 = 3076;
constexpr int DT_RANK = 49, D_STATE = 64;
constexpr int NCH = 8, CHT = 64;           // fused scan: 8 chunks x 64 t
constexpr int DGRP = (D_INNER + 15) / 16;  // 97 d-groups of 16
constexpr int THALO = 539;                 // 13 + 512 + 14 halo rows per b
// padded GEMM dims (K multiple of 64, N multiple of 128)
constexpr int KP_MODEL = 832;   // 769
constexpr int KP_INNER = 1600;  // 1538
constexpr int KP_DT    = 64;    // 49
constexpr int NP_IN  = 3200;    // 3076
constexpr int NP_X   = 256;     // 177
constexpr int NP_DT  = 1664;    // 1538
constexpr int NP_OUT = 896;     // 769
constexpr int KCONV  = 3456;    // 27*128 unified front-conv reduction
constexpr int NCONV  = 768;

DEV float fexp2(float x) { return __builtin_amdgcn_exp2f(x); }   // raw v_exp_f32
DEV float flog2(float x) { return __builtin_amdgcn_logf(x); }    // raw v_log_f32
DEV float frcp(float x) { return __builtin_amdgcn_rcpf(x); }     // raw v_rcp_f32
DEV float siluf(float v) { return v * frcp(1.f + fexp2(-1.44269504f * v)); }
DEV float softplusf(float v) {
  return fmaxf(v, 0.f) + 0.69314718f * flog2(1.f + fexp2(-1.44269504f * fabsf(v)));
}

DEV float wredx(float v) {
#pragma unroll
  for (int o = 1; o < 64; o <<= 1) v += __shfl_xor(v, o);
  return v;
}

// DPP / swizzle cross-lane helpers (VALU-pipe DPP where possible)
#define DPPF(v, ctrl) __uint_as_float((uint)__builtin_amdgcn_mov_dpp((int)__float_as_uint(v), (ctrl), 0xf, 0xf, true))
#define SWZF(v, pat) __uint_as_float((uint)__builtin_amdgcn_ds_swizzle((int)__float_as_uint(v), (pat)))

DEV void gload_lds16(const void* g, void* l) {
  __builtin_amdgcn_global_load_lds(
      (const __attribute__((address_space(1))) uint32_t*)(uintptr_t)g,
      (__attribute__((address_space(3))) uint32_t*)(uint32_t)(uintptr_t)l,
      16, 0, 0);
}

// ---------------- front end ----------------

// x (B,T,65) -> hpbfH (B,539,128) halo'd, rows 13..524 = silu(pointconv)
__global__ void front_pointconv(const float* __restrict__ x, const float* __restrict__ pw,
                                const float* __restrict__ pb, __hip_bfloat16* __restrict__ hpbfH) {
  int t = blockIdx.x, b = blockIdx.y, c = threadIdx.x;  // 128 threads
  __shared__ float xs[64];
  if (c < 64) xs[c] = x[((size_t)b * T + t) * 65 + c];
  __syncthreads();
  float acc = pb[c];
  const float4* pwr = (const float4*)(pw + c * 64);
#pragma unroll
  for (int i = 0; i < 16; ++i) {
    float4 w4 = pwr[i];
    acc = fmaf(w4.x, xs[4 * i + 0], acc);
    acc = fmaf(w4.y, xs[4 * i + 1], acc);
    acc = fmaf(w4.z, xs[4 * i + 2], acc);
    acc = fmaf(w4.w, xs[4 * i + 3], acc);
  }
  hpbfH[((size_t)b * THALO + 13 + t) * 128 + c] = __float2bfloat16(siluf(acc));
}

// zero halo rows 0..12 and 525..538 of each b
__global__ void zero_halo(__hip_bfloat16* __restrict__ h) {
  int i = blockIdx.x * 256 + threadIdx.x;
  if (i >= B * 27 * 128) return;
  int b = i / (27 * 128), r = i - b * 27 * 128;
  int row = r >> 7, c = r & 127;
  int rr = (row < 13) ? row : row + 512;
  h[((size_t)b * THALO + rr) * 128 + c] = __float2bfloat16(0.f);
}

// c1w/c2w/c3w -> Wfr(768, 3456) bf16; tail range fills bias vector
__global__ void build_conv_wb(const float* __restrict__ c1w, const float* __restrict__ c2w,
                              const float* __restrict__ c3w, const float* __restrict__ b1,
                              const float* __restrict__ b2, const float* __restrict__ b3,
                              __hip_bfloat16* __restrict__ Wfr, float* __restrict__ cb) {
  int total = NCONV * KCONV;
  for (int idx = blockIdx.x * 256 + threadIdx.x; idx < total + NCONV; idx += gridDim.x * 256) {
    if (idx < total) {
      int co = idx / KCONV, r = idx - co * KCONV;
      int j = r >> 7, ci = r & 127;
      float v = 0.f;
      if (co < 256) {
        int k = j - 12;
        if (k >= 0 && k < 3) v = c1w[((size_t)co * 128 + ci) * 3 + k];
      } else if (co < 512) {
        int k = j - 9;
        if (k >= 0 && k < 9) v = c2w[((size_t)(co - 256) * 128 + ci) * 9 + k];
      } else {
        v = c3w[((size_t)(co - 512) * 128 + ci) * 27 + j];
      }
      Wfr[idx] = __float2bfloat16(v);
    } else {
      int i = idx - total;
      cb[i] = (i < 256) ? b1[i] : (i < 512) ? b2[i - 256] : b3[i - 512];
    }
  }
}

// ---------------- weight conversion, all tensors both layers, 1 launch ----------------
__global__ void cvt_all(const float* __restrict__ Wi, const float* __restrict__ Wx,
                        const float* __restrict__ Wdt, const float* __restrict__ Wo,
                        __hip_bfloat16* __restrict__ Wibf, __hip_bfloat16* __restrict__ Wxbf,
                        __hip_bfloat16* __restrict__ Wdtbf, __hip_bfloat16* __restrict__ Wobf) {
  int l = blockIdx.y >> 2, t = blockIdx.y & 3;
  const float* src;
  __hip_bfloat16* dst;
  int N, K, Npad, Kpad;
  if (t == 0) { src = Wi + (size_t)l * D2 * D_MODEL; dst = Wibf + (size_t)l * NP_IN * KP_MODEL;
                N = D2; K = D_MODEL; Npad = NP_IN; Kpad = KP_MODEL; }
  else if (t == 1) { src = Wx + (size_t)l * (DT_RANK + 2 * D_STATE) * D_INNER;
                dst = Wxbf + (size_t)l * NP_X * KP_INNER;
                N = DT_RANK + 2 * D_STATE; K = D_INNER; Npad = NP_X; Kpad = KP_INNER; }
  else if (t == 2) { src = Wdt + (size_t)l * D_INNER * DT_RANK; dst = Wdtbf + (size_t)l * NP_DT * KP_DT;
                N = D_INNER; K = DT_RANK; Npad = NP_DT; Kpad = KP_DT; }
  else { src = Wo + (size_t)l * D_MODEL * D_INNER; dst = Wobf + (size_t)l * NP_OUT * KP_INNER;
                N = D_MODEL; K = D_INNER; Npad = NP_OUT; Kpad = KP_INNER; }
  int total = Npad * Kpad;
  for (int idx = blockIdx.x * 256 + threadIdx.x; idx < total; idx += gridDim.x * 256) {
    int n = idx / Kpad, k = idx - n * Kpad;
    float v = (n < N && k < K) ? src[(size_t)n * K + k] : 0.f;
    dst[idx] = __float2bfloat16(v);
  }
}

__global__ void zero_pad_cols(__hip_bfloat16* __restrict__ buf, int rows, int ld, int c0) {
  int w = ld - c0;
  int total = rows * w;
  int idx = blockIdx.x * 256 + threadIdx.x;
  if (idx < total) buf[(size_t)(idx / w) * ld + c0 + (idx % w)] = __float2bfloat16(0.f);
}

// ---------------- bf16 MFMA GEMM:  C[m][n] = sum_k A[m][k] * W[n][k] (+ epilogue) ----------------
// EPI 1: softplus(acc+bias[n]) -> packed bf16x2 {dt, dt*du} uint in (b,t,d);
// 6: split-K (KS = ldadd ways, balanced) raw partial store; 7: bf16 store to auxb[m*ldc+n]
// CONV=1: A is halo'd hpbfH with row stride 256B (im2col-free front conv).
// XCD-aware swizzle: weight-panel-major chunking so each XCD touches few N-panels.
template <int EPI, int CONV = 0>
__global__ __launch_bounds__(256) void gemm_bf16(const __hip_bfloat16* __restrict__ A,
                                                 const __hip_bfloat16* __restrict__ W,
                                                 float* __restrict__ C, int M, int Nreal, int Kp,
                                                 const float* extra, int ldadd, int ldc,
                                                 uint* auxv, __hip_bfloat16* auxb,
                                                 const __hip_bfloat16* auxr) {
  __shared__ __align__(16) __hip_bfloat16 As[128 * 64];
  __shared__ __align__(16) __hip_bfloat16 Bs[128 * 64];
  const int tid = threadIdx.x;
  const int wid = tid >> 6, lane = tid & 63;
  const int wr = wid >> 1, wc = wid & 1;
  int bx = blockIdx.x, by = blockIdx.y;
  {
    int gx = gridDim.x, gy = gridDim.y;
    int nwg = gx * gy;
    if ((nwg & 7) == 0) {
      int hid = by * gx + bx;                 // hw dispatch linear id (x fastest)
      int wkl = (hid & 7) * (nwg >> 3) + (hid >> 3);  // XCD k owns contiguous chunk
      bx = wkl / gy;                          // column-major: chunk = few bx (weight panels)
      by = wkl - bx * gy;
    }
  }
  const int m0 = by * 128, n0 = bx * 128;
  f32x4 acc[4][4] = {};
  const int lrow = lane >> 3;                                 // row within 8-row segment
  const int cbyte = ((lane & 7) << 4) ^ (lrow << 4);          // inverse-swizzled source col byte
  const char* Wb = (const char*)W;
  const size_t strideB = (size_t)Kp * 2;
  const char* ArowBase;
  size_t sA;
  if constexpr (CONV) {
    int brow = m0 >> 9;
    ArowBase = (const char*)A + (size_t)(brow * THALO + (m0 & 511)) * 256;
    sA = 256;
  } else {
    ArowBase = (const char*)A + (size_t)m0 * strideB;
    sA = strideB;
  }
  const int swz = (lane & 7) << 4;

  int kbeg = 0, kend = Kp;
  if constexpr (EPI == 6) {
    int KS = ldadd;
    int kiters = Kp >> 6;
    int zi = blockIdx.z;
    kbeg = ((kiters * zi) / KS) << 6;
    kend = ((kiters * (zi + 1)) / KS) << 6;
  }

  for (int k0 = kbeg; k0 < kend; k0 += 64) {
#pragma unroll
    for (int i = 0; i < 4; ++i) {
      int seg = i * 4 + wid;                                  // wave-uniform
      int row = seg * 8 + lrow;
      gload_lds16(ArowBase + (size_t)row * sA + k0 * 2 + cbyte, (char*)As + seg * 1024);
      gload_lds16(Wb + (size_t)(n0 + row) * strideB + k0 * 2 + cbyte, (char*)Bs + seg * 1024);
    }
    __syncthreads();
#pragma unroll
    for (int kk = 0; kk < 2; ++kk) {
      int kb = kk * 64 + ((lane >> 4) << 4);                  // byte offset of this lane's 8 bf16
      bf16x8v af[4], bfr[4];
#pragma unroll
      for (int mi = 0; mi < 4; ++mi) {
        int row = wr * 64 + mi * 16 + (lane & 15);
        af[mi] = *(const bf16x8v*)((const char*)As + row * 128 + (kb ^ swz));
      }
#pragma unroll
      for (int ni = 0; ni < 4; ++ni) {
        int row = wc * 64 + ni * 16 + (lane & 15);
        bfr[ni] = *(const bf16x8v*)((const char*)Bs + row * 128 + (kb ^ swz));
      }
#pragma unroll
      for (int mi = 0; mi < 4; ++mi)
#pragma unroll
        for (int ni = 0; ni < 4; ++ni)
          acc[mi][ni] = __builtin_amdgcn_mfma_f32_16x16x32_bf16(af[mi], bfr[ni], acc[mi][ni], 0, 0, 0);
    }
    __syncthreads();
  }

#pragma unroll
  for (int mi = 0; mi < 4; ++mi) {
#pragma unroll
    for (int ni = 0; ni < 4; ++ni) {
      int n = n0 + wc * 64 + ni * 16 + (lane & 15);
      if (n < Nreal) {
        int mb = m0 + wr * 64 + mi * 16 + ((lane >> 4) << 2);
#pragma unroll
        for (int v = 0; v < 4; ++v) {
          float val = acc[mi][ni][v];
          int m = mb + v;
          if constexpr (EPI == 1) {
            float dt = softplusf(val + extra[n]);
            float du = __bfloat162float(auxr[(size_t)m * KP_INNER + n]);
            uint lo = (__float_as_uint(dt) + 0x8000u) >> 16;
            uint hi = (__float_as_uint(dt * du) + 0x8000u) & 0xffff0000u;
            auxv[(size_t)m * D_INNER + n] = lo | hi;   // packed {dt, dt*du}, coalesced
          } else if constexpr (EPI == 6) {
            C[((size_t)blockIdx.z * M + m) * ldc + n] = val;
          } else if constexpr (EPI == 7) {
            auxb[(size_t)m * ldc + n] = __float2bfloat16(val);
          } else {
            C[(size_t)m * ldc + n] = val;
          }
        }
      }
    }
  }
}

// ---------------- fused combine kernels (block per row) ----------------
// front conv combine (4 partials) + silu + pe + rmsnorm -> hbuf, ubf
__global__ __launch_bounds__(256) void combine_conv_rms(const float* __restrict__ p,
                                                        const float* __restrict__ cb,
                                                        const float* __restrict__ x,
                                                        const float* __restrict__ rmsw,
                                                        float* __restrict__ h,
                                                        __hip_bfloat16* __restrict__ ubf) {
  int m = blockIdx.x;
  __shared__ float sh[D_MODEL];
  __shared__ float red[4];
  int wid = threadIdx.x >> 6, lane = threadIdx.x & 63;
  float ss = 0.f;
  for (int n = threadIdx.x; n < D_MODEL; n += 256) {
    float v;
    if (n < NCONV) {
      float s = cb[n];
#pragma unroll
      for (int z = 0; z < 4; ++z) s += p[((size_t)z * BT + m) * NCONV + n];
      v = siluf(s);
    } else {
      v = x[(size_t)m * 65 + 64];
    }
    sh[n] = v;
    h[(size_t)m * D_MODEL + n] = v;
    ss = fmaf(v, v, ss);
  }
  ss = wredx(ss);
  if (lane == 0) red[wid] = ss;
  __syncthreads();
  float sc = rsqrtf((red[0] + red[1] + red[2] + red[3]) * (1.f / D_MODEL) + 1e-6f);
  for (int i = threadIdx.x; i < KP_MODEL; i += 256) {
    float v = (i < D_MODEL) ? sh[i] * sc * rmsw[i] : 0.f;
    ubf[(size_t)m * KP_MODEL + i] = __float2bfloat16(v);
  }
}

// out_proj combine (4 partials) + residual + rmsnorm(next layer) -> hbuf, ubf
__global__ __launch_bounds__(256) void combine_out_rms(const float* __restrict__ p,
                                                       const float* __restrict__ rmsw,
                                                       float* __restrict__ h,
                                                       __hip_bfloat16* __restrict__ ubf) {
  int m = blockIdx.x;
  __shared__ float sh[D_MODEL];
  __shared__ float red[4];
  int wid = threadIdx.x >> 6, lane = threadIdx.x & 63;
  float ss = 0.f;
  for (int n = threadIdx.x; n < D_MODEL; n += 256) {
    size_t i = (size_t)m * D_MODEL + n;
    float v = h[i];
#pragma unroll
    for (int z = 0; z < 4; ++z) v += p[((size_t)z * BT + m) * D_MODEL + n];
    sh[n] = v;
    h[i] = v;
    ss = fmaf(v, v, ss);
  }
  ss = wredx(ss);
  if (lane == 0) red[wid] = ss;
  __syncthreads();
  float sc = rsqrtf((red[0] + red[1] + red[2] + red[3]) * (1.f / D_MODEL) + 1e-6f);
  for (int i = threadIdx.x; i < KP_MODEL; i += 256) {
    float v = (i < D_MODEL) ? sh[i] * sc * rmsw[i] : 0.f;
    ubf[(size_t)m * KP_MODEL + i] = __float2bfloat16(v);
  }
}

// last layer: out_proj combine (4 partials) + residual + layernorm + classifier head -> out
__global__ __launch_bounds__(256) void combine_ln(const float* __restrict__ p,
                                                  const float* __restrict__ h,
                                                  const float* __restrict__ lnw,
                                                  const float* __restrict__ lnb,
                                                  const float* __restrict__ ow,
                                                  const float* __restrict__ ob,
                                                  float* __restrict__ out) {
  int row = blockIdx.x;
  __shared__ float sh[D_MODEL];
  __shared__ float red[4];
  int wid = threadIdx.x >> 6, lane = threadIdx.x & 63;
  float s = 0.f;
  for (int i = threadIdx.x; i < D_MODEL; i += 256) {
    size_t ix = (size_t)row * D_MODEL + i;
    float v = h[ix];
#pragma unroll
    for (int z = 0; z < 4; ++z) v += p[((size_t)z * BT + row) * D_MODEL + i];
    sh[i] = v;
    s += v;
  }
  s = wredx(s);
  if (lane == 0) red[wid] = s;
  __syncthreads();
  float mean = (red[0] + red[1] + red[2] + red[3]) * (1.f / D_MODEL);
  __syncthreads();
  float vs = 0.f;
  for (int i = threadIdx.x; i < D_MODEL; i += 256) { float dd = sh[i] - mean; vs = fmaf(dd, dd, vs); }
  vs = wredx(vs);
  if (lane == 0) red[wid] = vs;
  __syncthreads();
  float var = (red[0] + red[1] + red[2] + red[3]) * (1.f / D_MODEL);
  float inv = rsqrtf(var + 1e-5f);
  for (int i = threadIdx.x; i < D_MODEL; i += 256)
    sh[i] = (sh[i] - mean) * inv * lnw[i] + lnb[i];
  __syncthreads();
  for (int c = wid; c < 10; c += 4) {
    float acc = 0.f;
    for (int i = lane; i < D_MODEL; i += 64) acc = fmaf(sh[i], ow[(size_t)c * D_MODEL + i], acc);
    acc = wredx(acc);
    if (lane == 0) out[(size_t)row * 10 + c] = acc + ob[c];
  }
}

// x_proj combine: parts (8, BT, 256) -> dtbf (BT,64) bf16 + bcbf (BT,64) packed {B,C} bf16x2
__global__ void combine_xproj(const float* __restrict__ p, __hip_bfloat16* __restrict__ dtbf,
                              __hip_bfloat16* __restrict__ bcb) {
  int i = blockIdx.x * 256 + threadIdx.x;
  if (i >= BT * 192) return;
  int m = i / 192, n = i - m * 192;
  if (n >= DT_RANK + 2 * D_STATE) return;
  float v = 0.f;
#pragma unroll
  for (int z = 0; z < 8; ++z) v += p[((size_t)z * BT + m) * 256 + n];
  if (n < 64) dtbf[(size_t)m * 64 + n] = __float2bfloat16(n < DT_RANK ? v : 0.f);
  if (n >= DT_RANK && n < DT_RANK + D_STATE)
    bcb[((size_t)m * 64 + (n - DT_RANK)) * 2] = __float2bfloat16(v);          // B -> lo
  else if (n >= DT_RANK + D_STATE)
    bcb[((size_t)m * 64 + (n - DT_RANK - D_STATE)) * 2 + 1] = __float2bfloat16(v);  // C -> hi
}

// ---------------- depthwise causal conv (k=4) + silu, 2 d per thread (packed) ----------------
__global__ void dwconv_silu(const __hip_bfloat16* __restrict__ xz, const float* __restrict__ cw,
                            const float* __restrict__ cb, __hip_bfloat16* __restrict__ xinbf) {
  int idx = blockIdx.x * 256 + threadIdx.x;
  if (idx >= BT * 769) return;                 // D_INNER/2 pairs
  int bt = idx / 769;
  int dd = idx - bt * 769;                     // pair index; d = 2*dd, d+1
  int d = dd * 2;
  int t = bt & (T - 1);
  float4 w0 = *(const float4*)(cw + (size_t)d * 4);
  float4 w1 = *(const float4*)(cw + (size_t)(d + 1) * 4);
  float acc0 = cb[d], acc1 = cb[d + 1];
  const uint* col = (const uint*)(xz + (size_t)bt * D2) + dd;
  float wk0[4] = {w0.x, w0.y, w0.z, w0.w};
  float wk1[4] = {w1.x, w1.y, w1.z, w1.w};
#pragma unroll
  for (int k = 0; k < 4; ++k) {
    int tt = t + k - 3;
    uint v = (tt >= 0) ? col[(ptrdiff_t)(k - 3) * (D2 / 2)] : 0u;
    float lo = __uint_as_float(v << 16);
    float hi = __uint_as_float(v & 0xffff0000u);
    acc0 = fmaf(wk0[k], lo, acc0);
    acc1 = fmaf(wk1[k], hi, acc1);
  }
  acc0 = siluf(acc0);
  acc1 = siluf(acc1);
  uint lo16 = (__float_as_uint(acc0) + 0x8000u) >> 16;   // RTN-ish bf16 pack
  uint hi16 = (__float_as_uint(acc1) + 0x8000u) & 0xffff0000u;
  ((uint*)xinbf)[(size_t)bt * (KP_INNER / 2) + dd] = lo16 | hi16;
}

// ---------------- fused single-pass scan: 512 threads, 8 waves x 2 d/wave, 16 d/block ----------------
// r16 config (measured optimum). dtdu packed bf16x2 in global; unpacked in stage().
// Each wave carries TWO independent h chains; LDS staging double-buffered per 64-t chunk;
// bc via register ping-pong with pointer-bump literal offsets. Reduce: DPP + 3 DS ops.

#define FCOMP2(REG, T0L, T0G)                                                \
  {                                                                          \
    float4 qa0 = *(const float4*)&dtsA[(T0L)];                               \
    float4 qa1 = *(const float4*)&dtsA[(T0L) + 4];                           \
    float4 ua0 = *(const float4*)&dtusA[(T0L)];                              \
    float4 ua1 = *(const float4*)&dtusA[(T0L) + 4];                          \
    float4 qb0 = *(const float4*)&dtsB[(T0L)];                               \
    float4 qb1 = *(const float4*)&dtsB[(T0L) + 4];                           \
    float4 ub0 = *(const float4*)&dtusB[(T0L)];                              \
    float4 ub1 = *(const float4*)&dtusB[(T0L) + 4];                          \
    float dtvA[8] = {qa0.x, qa0.y, qa0.z, qa0.w, qa1.x, qa1.y, qa1.z, qa1.w};\
    float duvA[8] = {ua0.x, ua0.y, ua0.z, ua0.w, ua1.x, ua1.y, ua1.z, ua1.w};\
    float dtvB[8] = {qb0.x, qb0.y, qb0.z, qb0.w, qb1.x, qb1.y, qb1.z, qb1.w};\
    float duvB[8] = {ub0.x, ub0.y, ub0.z, ub0.w, ub1.x, ub1.y, ub1.z, ub1.w};\
    float vvA[8], vvB[8];                                                    \
    _Pragma("unroll") for (int k = 0; k < 8; ++k) {                          \
      float Bv = __uint_as_float(REG[k] << 16);                              \
      float Cv = __uint_as_float(REG[k] & 0xffff0000u);                      \
      hA = fmaf(fexp2(dtvA[k] * a2A), hA, duvA[k] * Bv);                     \
      hB = fmaf(fexp2(dtvB[k] * a2B), hB, duvB[k] * Bv);                     \
      vvA[k] = hA * Cv;                                                      \
      vvB[k] = hB * Cv;                                                      \
    }                                                                        \
    _Pragma("unroll") for (int k = 0; k < 4; ++k) {                          \
      float sA = bb0 ? vvA[k] : vvA[k + 4];                                  \
      float kA = bb0 ? vvA[k + 4] : vvA[k];                                  \
      vvA[k] = kA + DPPF(sA, 0xB1);                                          \
      float sB = bb0 ? vvB[k] : vvB[k + 4];                                  \
      float kB = bb0 ? vvB[k + 4] : vvB[k];                                  \
      vvB[k] = kB + DPPF(sB, 0xB1);                                          \
    }                                                                        \
    _Pragma("unroll") for (int k = 0; k < 2; ++k) {                          \
      float sA = bb1 ? vvA[k] : vvA[k + 2];                                  \
      float kA = bb1 ? vvA[k + 2] : vvA[k];                                  \
      vvA[k] = kA + DPPF(sA, 0x4E);                                          \
      float sB = bb1 ? vvB[k] : vvB[k + 2];                                  \
      float kB = bb1 ? vvB[k + 2] : vvB[k];                                  \
      vvB[k] = kB + DPPF(sB, 0x4E);                                          \
    }                                                                        \
    {                                                                        \
      float sA = bb2 ? vvA[0] : vvA[1];                                      \
      float kA = bb2 ? vvA[1] : vvA[0];                                      \
      vvA[0] = kA + SWZF(sA, 0x101F);                                        \
      float sB = bb2 ? vvB[0] : vvB[1];                                      \
      float kB = bb2 ? vvB[1] : vvB[0];                                      \
      vvB[0] = kB + SWZF(sB, 0x101F);                                        \
    }                                                                        \
    float yA = vvA[0], yB = vvB[0];                                          \
    yA += DPPF(yA, 0x128);  yB += DPPF(yB, 0x128);                           \
    yA += SWZF(yA, 0x401F); yB += SWZF(yB, 0x401F);                          \
    yA += __shfl_xor(yA, 32); yB += __shfl_xor(yB, 32);                      \
    if (lane < 8) {                                                          \
      int trow = ((T0L) + brl) * 17;                                         \
      if (vA) {                                                              \
        float yo = (yA + xinS[trow + 2 * wid] * dskA) * siluf(xzS[trow + 2 * wid]); \
        ybf[(rb + (T0G) + brl) * KP_INNER + dA] = __float2bfloat16(yo);      \
      }                                                                      \
      if (vB) {                                                              \
        float yo = (yB + xinS[trow + 2 * wid + 1] * dskB) * siluf(xzS[trow + 2 * wid + 1]); \
        ybf[(rb + (T0G) + brl) * KP_INNER + dB] = __float2bfloat16(yo);      \
      }                                                                      \
    }                                                                        \
  }

__global__ __launch_bounds__(512) void scan_fused(const uint* __restrict__ bcp16,
                                                  const uint* __restrict__ dtduP,
                                                  const __hip_bfloat16* __restrict__ xinbf,
                                                  const __hip_bfloat16* __restrict__ xzbf,
                                                  const float* __restrict__ A_log,
                                                  const float* __restrict__ Dskip,
                                                  __hip_bfloat16* __restrict__ ybf) {
  __shared__ __align__(16) float dts[2][16 * 68];
  __shared__ __align__(16) float dtus[2][16 * 68];
  __shared__ float xins[2][CHT * 17];
  __shared__ float xzs[2][CHT * 17];
  int tid = threadIdx.x, wid = tid >> 6, lane = tid & 63;
  int dg = blockIdx.x % DGRP, b = blockIdx.x / DGRP;
  int d0 = dg * 16;
  int dA = d0 + wid * 2, dB = dA + 1;
  bool vA = (dA < D_INNER), vB = (dB < D_INNER);
  int dcA = vA ? dA : (D_INNER - 1);
  int dcB = vB ? dB : (D_INNER - 1);
  const size_t rb = (size_t)b * T;

  auto stage = [&](int c, int s) {
#pragma unroll
    for (int j = 0; j < 2; ++j) {
      int t2 = tid + j * 512;
      int stt = t2 >> 4, sdd = t2 & 15;
      uint dq = dtduP[(rb + c * CHT + stt) * D_INNER + d0 + sdd];
      dts[s][sdd * 68 + stt] = __uint_as_float(dq << 16);
      dtus[s][sdd * 68 + stt] = __uint_as_float(dq & 0xffff0000u);
      xins[s][stt * 17 + sdd] = __bfloat162float(xinbf[(rb + c * CHT + stt) * KP_INNER + d0 + sdd]);
      xzs[s][stt * 17 + sdd] = __bfloat162float(xzbf[(rb + c * CHT + stt) * D2 + D_INNER + d0 + sdd]);
    }
  };

  stage(0, 0);

  const bool bb2 = lane & 4, bb1 = lane & 2, bb0 = lane & 1;
  const int brl = ((lane & 1) << 2) | (lane & 2) | ((lane & 4) >> 2);
  float a2A = -__expf(A_log[(size_t)dcA * D_STATE + lane]) * 1.44269504f;
  float a2B = -__expf(A_log[(size_t)dcB * D_STATE + lane]) * 1.44269504f;
  float dskA = Dskip[dcA], dskB = Dskip[dcB];
  float hA = 0.f, hB = 0.f;
  const uint* bgp = bcp16 + rb * 64 + lane;

  __syncthreads();

  uint bA[8], bB[8];
#pragma unroll
  for (int k = 0; k < 8; ++k) bA[k] = bgp[k * 64];
  const uint* bq = bgp;  // pointer-bump: advances 1024 elems (16 t) per group

  for (int ch = 0; ch < NCH; ++ch) {
    int s = ch & 1;
    const float* dtsA = &dts[s][(2 * wid) * 68];
    const float* dtusA = &dtus[s][(2 * wid) * 68];
    const float* dtsB = &dts[s][(2 * wid + 1) * 68];
    const float* dtusB = &dtus[s][(2 * wid + 1) * 68];
    const float* xinS = &xins[s][0];
    const float* xzS = &xzs[s][0];
    if (ch + 1 < NCH) stage(ch + 1, s ^ 1);
#pragma unroll
    for (int gi = 0; gi < 4; ++gi) {
      int t0l = gi * 16;
      int t0g = ch * CHT + t0l;
#pragma unroll
      for (int k = 0; k < 8; ++k) bB[k] = bq[512 + k * 64];   // literal offsets 2048..3840B
      FCOMP2(bA, t0l, t0g);
      bq += 1024;
      if (!(ch == NCH - 1 && gi == 3)) {
#pragma unroll
        for (int k = 0; k < 8; ++k) bA[k] = bq[k * 64];       // literal offsets 0..1792B
      }
      FCOMP2(bB, t0l + 8, t0g + 8);
    }
    __syncthreads();
  }
}

// ---------------- launcher ----------------
extern "C" void kernel_launch(void* const* d_in, const int* in_sizes, int n_in,
                              void* d_out, int out_size, void* d_ws, size_t ws_size,
                              hipStream_t stream) {
  const float* x    = (const float*)d_in[0];
  const float* pcw  = (const float*)d_in[1];
  const float* pcb  = (const float*)d_in[2];
  const float* c1w  = (const float*)d_in[3];
  const float* c1b  = (const float*)d_in[4];
  const float* c2w  = (const float*)d_in[5];
  const float* c2b  = (const float*)d_in[6];
  const float* c3w  = (const float*)d_in[7];
  const float* c3b  = (const float*)d_in[8];
  const float* lnw  = (const float*)d_in[9];
  const float* lnb  = (const float*)d_in[10];
  const float* ow   = (const float*)d_in[11];
  const float* ob   = (const float*)d_in[12];
  const float* rmsw = (const float*)d_in[13];
  const float* Wi   = (const float*)d_in[14];
  const float* dww  = (const float*)d_in[15];
  const float* dwb  = (const float*)d_in[16];
  const float* Wx   = (const float*)d_in[17];
  const float* Wdt  = (const float*)d_in[18];
  const float* dtbv = (const float*)d_in[19];
  const float* Alog = (const float*)d_in[20];
  const float* Dsk  = (const float*)d_in[21];
  const float* Wo   = (const float*)d_in[22];
  float* out = (float*)d_out;

  char* w = (char*)d_ws;
  auto alloc = [&](size_t n) { char* p = w; w += (n + 255) & ~(size_t)255; return p; };
  // shared region: front-end buffers (dead after front GEMM) aliased with scan temps
  constexpr size_t REGION = 26400000;
  char* region = alloc(REGION);
  __hip_bfloat16* hpbfH = (__hip_bfloat16*)region;                   // 552,448 B (halo'd)
  __hip_bfloat16* Wfr  = (__hip_bfloat16*)(region + 14756096);       // 5,308,416 B
  float* cb768         = (float*)(region + 20065024);                // 3,072 B
  uint* dtduP          = (uint*)region;                              // 12,599,296 B (layer phase)
  __hip_bfloat16* bcbf = (__hip_bfloat16*)(region + 25198592);       // 524,288 B packed {B,C}

  float* hbuf          = (float*)alloc((size_t)BT * D_MODEL * 4);
  __hip_bfloat16* ubf  = (__hip_bfloat16*)alloc((size_t)BT * KP_MODEL * 2);
  __hip_bfloat16* xzbf = (__hip_bfloat16*)alloc((size_t)BT * D2 * 2);
  __hip_bfloat16* xinbf= (__hip_bfloat16*)alloc((size_t)BT * KP_INNER * 2);
  __hip_bfloat16* dtbf = (__hip_bfloat16*)alloc((size_t)BT * KP_DT * 2);
  __hip_bfloat16* ybf  = (__hip_bfloat16*)alloc((size_t)BT * KP_INNER * 2);
  __hip_bfloat16* Wibf = (__hip_bfloat16*)alloc((size_t)2 * NP_IN * KP_MODEL * 2);
  __hip_bfloat16* Wxbf = (__hip_bfloat16*)alloc((size_t)2 * NP_X * KP_INNER * 2);
  __hip_bfloat16* Wdtbf= (__hip_bfloat16*)alloc((size_t)2 * NP_DT * KP_DT * 2);
  __hip_bfloat16* Wobf = (__hip_bfloat16*)alloc((size_t)2 * NP_OUT * KP_INNER * 2);
  float* parts         = (float*)alloc((size_t)4 * BT * D_MODEL * 4);          // 25.2 MB split-K partials

  zero_halo<<<(B * 27 * 128 + 255) / 256, 256, 0, stream>>>(hpbfH);
  front_pointconv<<<dim3(T, B), 128, 0, stream>>>(x, pcw, pcb, hpbfH);
  build_conv_wb<<<2048, 256, 0, stream>>>(c1w, c2w, c3w, c1b, c2b, c3b, Wfr, cb768);
  cvt_all<<<dim3(1024, 8), 256, 0, stream>>>(Wi, Wx, Wdt, Wo, Wibf, Wxbf, Wdtbf, Wobf);
  gemm_bf16<6, 1><<<dim3(NCONV / 128, BT / 128, 4), 256, 0, stream>>>(
      hpbfH, Wfr, parts, BT, NCONV, KCONV, nullptr, 4, NCONV, nullptr, nullptr, nullptr);
  combine_conv_rms<<<BT, 256, 0, stream>>>(parts, cb768, x, rmsw, hbuf, ubf);
  // pad columns written once (scan/dwconv never touch cols >= D_INNER)
  zero_pad_cols<<<(BT * (KP_INNER - D_INNER) + 255) / 256, 256, 0, stream>>>(xinbf, BT, KP_INNER, D_INNER);
  zero_pad_cols<<<(BT * (KP_INNER - D_INNER) + 255) / 256, 256, 0, stream>>>(ybf, BT, KP_INNER, D_INNER);

  for (int l = 0; l < 2; ++l) {
    const float* Al = Alog + (size_t)l * D_INNER * D_STATE;
    gemm_bf16<7><<<dim3(NP_IN / 128, BT / 128), 256, 0, stream>>>(
        ubf, Wibf + (size_t)l * NP_IN * KP_MODEL, nullptr, BT, D2, KP_MODEL,
        nullptr, 0, D2, nullptr, xzbf, nullptr);
    dwconv_silu<<<(BT * 769 + 255) / 256, 256, 0, stream>>>(xzbf, dww + (size_t)l * D_INNER * 4,
                                                            dwb + (size_t)l * D_INNER, xinbf);
    gemm_bf16<6><<<dim3(NP_X / 128, BT / 128, 8), 256, 0, stream>>>(
        xinbf, Wxbf + (size_t)l * NP_X * KP_INNER, parts, BT,
        DT_RANK + 2 * D_STATE, KP_INNER, nullptr, 8, 256, nullptr, nullptr, nullptr);
    combine_xproj<<<(BT * 192 + 255) / 256, 256, 0, stream>>>(parts, dtbf, bcbf);
    gemm_bf16<1><<<dim3(NP_DT / 128, BT / 128), 256, 0, stream>>>(
        dtbf, Wdtbf + (size_t)l * NP_DT * KP_DT, nullptr, BT, D_INNER, KP_DT,
        dtbv + (size_t)l * D_INNER, 0, 0, dtduP, nullptr, xinbf);
    scan_fused<<<dim3(B * DGRP), 512, 0, stream>>>((const uint*)bcbf, dtduP, xinbf, xzbf, Al,
                                                   Dsk + (size_t)l * D_INNER, ybf);
    gemm_bf16<6><<<dim3(NP_OUT / 128, BT / 128, 4), 256, 0, stream>>>(
        ybf, Wobf + (size_t)l * NP_OUT * KP_INNER, parts, BT, D_MODEL, KP_INNER,
        nullptr, 4, D_MODEL, nullptr, nullptr, nullptr);
    if (l == 0) {
      combine_out_rms<<<BT, 256, 0, stream>>>(parts, rmsw + D_MODEL, hbuf, ubf);
    } else {
      combine_ln<<<BT, 256, 0, stream>>>(parts, hbuf, lnw, lnb, ow, ob, out);
    }
  }
}